// Round 1
// 4649.533 us; speedup vs baseline: 1.0053x; 1.0053x over previous
//
#include <hip/hip_runtime.h>

#define NB 64
#define NT 1024
#define DIN 12
#define NH 256
#define NG 1024
#define NCLS 17
#define TCL 128
#define NCHUNK 8
#define XPS ((size_t)2 * NB * TCL * NG)   // floats per xp1 chunk buffer

typedef _Float16 f16;
typedef __attribute__((ext_vector_type(2))) _Float16 half2_t;
typedef __attribute__((ext_vector_type(8))) _Float16 f16x8;
typedef __attribute__((ext_vector_type(4))) float f32x4;
typedef unsigned int uint;
typedef unsigned short ushort;

__device__ __forceinline__ float sigm(float v) { return 1.0f / (1.0f + __expf(-v)); }
__device__ __forceinline__ float tanh_(float v) {
    v = fminf(fmaxf(v, -15.0f), 15.0f);
    float e = __expf(2.0f * v);
    return (e - 1.0f) / (e + 1.0f);
}
__device__ __forceinline__ float dot2(uint w, uint h, float c) {
    return __builtin_amdgcn_fdot2(__builtin_bit_cast(half2_t, w),
                                  __builtin_bit_cast(half2_t, h), c, false);
}
__device__ __forceinline__ uint pack16(float a, float b) {
    union { f16 h[2]; uint u; } cv; cv.h[0] = (f16)a; cv.h[1] = (f16)b; return cv.u;
}
__device__ __forceinline__ uint pkrtz(float a, float b) {
    return __builtin_bit_cast(uint, __builtin_amdgcn_cvt_pkrtz(a, b));
}
__device__ __forceinline__ ushort hbits(f16 v) {
    union { f16 h; ushort u; } cv; cv.h = v; return cv.u;
}
__device__ __forceinline__ uint rdlane(uint v, int l) {
    return (uint)__builtin_amdgcn_readlane((int)v, l);
}

// ---------------------------------------------------------------------------
// Round-12 interleave machinery.
// In-order issue + q-major dependent dot quads = (latency-2) stall per dot.
// Comp-major over 8 accumulators (A-bank for packed comps x,z; B-bank for
// y,w): same-accumulator reuse distance = 8 instrs (16 cyc), all consecutive
// dots independent.
// ---------------------------------------------------------------------------
#define RDL4(HV, G, S0, S1, S2, S3)                                           \
    uint S0 = rdlane((HV).x, (G)), S1 = rdlane((HV).y, (G)),                  \
         S2 = rdlane((HV).z, (G)), S3 = rdlane((HV).w, (G))

#define DOTS_GRP(AH, BH, W0, W1, W2, W3, S0, S1, S2, S3) do {                 \
    AH[0] = dot2((W0).x, (S0), AH[0]); AH[1] = dot2((W1).x, (S0), AH[1]);     \
    AH[2] = dot2((W2).x, (S0), AH[2]); AH[3] = dot2((W3).x, (S0), AH[3]);     \
    BH[0] = dot2((W0).y, (S1), BH[0]); BH[1] = dot2((W1).y, (S1), BH[1]);     \
    BH[2] = dot2((W2).y, (S1), BH[2]); BH[3] = dot2((W3).y, (S1), BH[3]);     \
    AH[0] = dot2((W0).z, (S2), AH[0]); AH[1] = dot2((W1).z, (S2), AH[1]);     \
    AH[2] = dot2((W2).z, (S2), AH[2]); AH[3] = dot2((W3).z, (S2), AH[3]);     \
    BH[0] = dot2((W0).w, (S3), BH[0]); BH[1] = dot2((W1).w, (S3), BH[1]);     \
    BH[2] = dot2((W2).w, (S3), BH[2]); BH[3] = dot2((W3).w, (S3), BH[3]);     \
} while (0)

// AGPR-weight group: per packed component, 4 accvgpr reads then 4 independent
// dots (only 4 weight temps live; reads space the dot stream further).
#define AGPR_GRP(AH, BH, AW, M, S0, S1, S2, S3) do {                          \
    uint w0_, w1_, w2_, w3_;                                                  \
    asm volatile("v_accvgpr_read_b32 %0, %1" : "=v"(w0_) : "a"(AW[(0*15+(M))*4+0])); \
    asm volatile("v_accvgpr_read_b32 %0, %1" : "=v"(w1_) : "a"(AW[(1*15+(M))*4+0])); \
    asm volatile("v_accvgpr_read_b32 %0, %1" : "=v"(w2_) : "a"(AW[(2*15+(M))*4+0])); \
    asm volatile("v_accvgpr_read_b32 %0, %1" : "=v"(w3_) : "a"(AW[(3*15+(M))*4+0])); \
    AH[0] = dot2(w0_, (S0), AH[0]); AH[1] = dot2(w1_, (S0), AH[1]);           \
    AH[2] = dot2(w2_, (S0), AH[2]); AH[3] = dot2(w3_, (S0), AH[3]);           \
    asm volatile("v_accvgpr_read_b32 %0, %1" : "=v"(w0_) : "a"(AW[(0*15+(M))*4+1])); \
    asm volatile("v_accvgpr_read_b32 %0, %1" : "=v"(w1_) : "a"(AW[(1*15+(M))*4+1])); \
    asm volatile("v_accvgpr_read_b32 %0, %1" : "=v"(w2_) : "a"(AW[(2*15+(M))*4+1])); \
    asm volatile("v_accvgpr_read_b32 %0, %1" : "=v"(w3_) : "a"(AW[(3*15+(M))*4+1])); \
    BH[0] = dot2(w0_, (S1), BH[0]); BH[1] = dot2(w1_, (S1), BH[1]);           \
    BH[2] = dot2(w2_, (S1), BH[2]); BH[3] = dot2(w3_, (S1), BH[3]);           \
    asm volatile("v_accvgpr_read_b32 %0, %1" : "=v"(w0_) : "a"(AW[(0*15+(M))*4+2])); \
    asm volatile("v_accvgpr_read_b32 %0, %1" : "=v"(w1_) : "a"(AW[(1*15+(M))*4+2])); \
    asm volatile("v_accvgpr_read_b32 %0, %1" : "=v"(w2_) : "a"(AW[(2*15+(M))*4+2])); \
    asm volatile("v_accvgpr_read_b32 %0, %1" : "=v"(w3_) : "a"(AW[(3*15+(M))*4+2])); \
    AH[0] = dot2(w0_, (S2), AH[0]); AH[1] = dot2(w1_, (S2), AH[1]);           \
    AH[2] = dot2(w2_, (S2), AH[2]); AH[3] = dot2(w3_, (S2), AH[3]);           \
    asm volatile("v_accvgpr_read_b32 %0, %1" : "=v"(w0_) : "a"(AW[(0*15+(M))*4+3])); \
    asm volatile("v_accvgpr_read_b32 %0, %1" : "=v"(w1_) : "a"(AW[(1*15+(M))*4+3])); \
    asm volatile("v_accvgpr_read_b32 %0, %1" : "=v"(w2_) : "a"(AW[(2*15+(M))*4+3])); \
    asm volatile("v_accvgpr_read_b32 %0, %1" : "=v"(w3_) : "a"(AW[(3*15+(M))*4+3])); \
    BH[0] = dot2(w0_, (S3), BH[0]); BH[1] = dot2(w1_, (S3), BH[1]);           \
    BH[2] = dot2(w2_, (S3), BH[2]); BH[3] = dot2(w3_, (S3), BH[3]);           \
} while (0)

// ---------------------------------------------------------------------------
// k_prep: layer-specific fp16 packing. kp = k/2 (0..127).  (unchanged)
// ---------------------------------------------------------------------------
__global__ void k_prep(const float* __restrict__ w_hh0, const float* __restrict__ w_hh1,
                       const float* __restrict__ w_ih0, const float* __restrict__ w_ih1,
                       const float* __restrict__ b_ih1, const float* __restrict__ b_hh1,
                       uint* __restrict__ Wkv0, uint* __restrict__ Wka0,
                       uint* __restrict__ Wkl0, uint* __restrict__ wih0p,
                       uint* __restrict__ Wkv1, uint* __restrict__ Wka1,
                       uint* __restrict__ Wkl1,
                       f16* __restrict__ wih1h, float* __restrict__ bsum1) {
    int i = blockIdx.x * 256 + threadIdx.x;
    // ---- layer 0 ----
    if (i < 2 * 4 * 256 * 40) {            // Wkv0
        int kp = i % 40; int r = i / 40;
        int t = r & 255, q = (r >> 8) & 3, dir = r >> 10;
        const float* row = w_hh0 + (size_t)dir * NG * NH + (size_t)(q * 256 + t) * NH;
        Wkv0[i] = pack16(row[2 * kp], row[2 * kp + 1]);
    }
    if (i < 2 * 4 * 256 * 60) {            // Wka0
        int kp = 40 + (i % 60); int r = i / 60;
        int t = r & 255, q = (r >> 8) & 3, dir = r >> 10;
        const float* row = w_hh0 + (size_t)dir * NG * NH + (size_t)(q * 256 + t) * NH;
        Wka0[i] = pack16(row[2 * kp], row[2 * kp + 1]);
    }
    if (i < 2 * 4 * 7 * 256 * 4) {         // Wkl0
        int j = i & 3; int u = i >> 2;
        int t = u & 255; int v = u >> 8;
        int g = v % 7; int w2 = v / 7;
        int q = w2 & 3, dir = w2 >> 2;
        int kp = 100 + 4 * g + j;
        const float* row = w_hh0 + (size_t)dir * NG * NH + (size_t)(q * 256 + t) * NH;
        Wkl0[i] = pack16(row[2 * kp], row[2 * kp + 1]);
    }
    if (i < 2 * 4 * 6 * 256) {             // wih0p
        int t = i & 255; int r = i >> 8;
        int dp = r % 6, q = (r / 6) & 3, dd = r / 24;
        const float* row = w_ih0 + ((size_t)dd * NG + q * 256 + t) * DIN;
        wih0p[i] = pack16(row[2 * dp], row[2 * dp + 1]);
    }
    // ---- layer 1 ----
    if (i < 2 * 4 * 256 * 48) {            // Wkv1
        int kp = i % 48; int r = i / 48;
        int t = r & 255, q = (r >> 8) & 3, dir = r >> 10;
        const float* row = w_hh1 + (size_t)dir * NG * NH + (size_t)(q * 256 + t) * NH;
        Wkv1[i] = pack16(row[2 * kp], row[2 * kp + 1]);
    }
    if (i < 2 * 4 * 256 * 60) {            // Wka1 (kp 48..107)
        int kp = 48 + (i % 60); int r = i / 60;
        int t = r & 255, q = (r >> 8) & 3, dir = r >> 10;
        const float* row = w_hh1 + (size_t)dir * NG * NH + (size_t)(q * 256 + t) * NH;
        Wka1[i] = pack16(row[2 * kp], row[2 * kp + 1]);
    }
    if (i < 2 * 4 * 5 * 256 * 4) {         // Wkl1 (kp 108..127)
        int j = i & 3; int u = i >> 2;
        int t = u & 255; int v = u >> 8;
        int g = v % 5; int w2 = v / 5;
        int q = w2 & 3, dir = w2 >> 2;
        int kp = 108 + 4 * g + j;
        const float* row = w_hh1 + (size_t)dir * NG * NH + (size_t)(q * 256 + t) * NH;
        Wkl1[i] = pack16(row[2 * kp], row[2 * kp + 1]);
    }
    if (i < 2 * NG * 2 * NH) wih1h[i] = (f16)w_ih1[i];
    if (i < 2 * NG) bsum1[i] = b_ih1[i] + b_hh1[i];
}

// ---------------------------------------------------------------------------
// rec0_seq: layer-0 recurrence, round-12 comp-major interleave.
// One block per (dir,batch), 256 threads. Lane t owns unit t (4 gate rows).
// Weights: 160 VGPR + 240 AGPR uints + 112 KB LDS. h broadcast: one b128
// LDS read/lane + readlane. LDS-weight groups interleaved between AGPR
// groups so their ~120-cyc latency is covered by independent VALU work.
// ---------------------------------------------------------------------------
__device__ void rec0_seq(char* smem, int rb,
                         const uint* __restrict__ Wkv0, const uint* __restrict__ Wka0,
                         const uint4* __restrict__ Wkl0, const uint* __restrict__ wih0p,
                         const float* __restrict__ b_ih0, const float* __restrict__ b_hh0,
                         const float* __restrict__ x, f16* __restrict__ out0h,
                         float* __restrict__ hst, float* __restrict__ cst) {
    uint4* wlds4 = (uint4*)smem;                         // [4][7][256] uint4 = 112 KB
    ushort* hs16 = (ushort*)(smem + 114688);             // [2 par][256] f16 = 1 KB

    const int tid = threadIdx.x;
    const int dir = rb >> 6;
    const int b = rb & 63;

    for (int n = tid; n < 7168; n += 256) wlds4[n] = Wkl0[dir * 7168 + n];

    uint4 wrv[4][10];
    #pragma unroll
    for (int q = 0; q < 4; ++q) {
        const uint* src = Wkv0 + (size_t)((dir * 4 + q) * 256 + tid) * 40;
        #pragma unroll
        for (int m = 0; m < 10; ++m) wrv[q][m] = *(const uint4*)(src + m * 4);
    }

    uint aw[240];
    #pragma unroll
    for (int q = 0; q < 4; ++q) {
        const uint* src = Wka0 + (size_t)((dir * 4 + q) * 256 + tid) * 60;
        #pragma unroll
        for (int m = 0; m < 15; ++m) {
            uint4 v = *(const uint4*)(src + m * 4);
            asm volatile("v_accvgpr_write_b32 %0, %1" : "=a"(aw[(q * 15 + m) * 4 + 0]) : "v"(v.x));
            asm volatile("v_accvgpr_write_b32 %0, %1" : "=a"(aw[(q * 15 + m) * 4 + 1]) : "v"(v.y));
            asm volatile("v_accvgpr_write_b32 %0, %1" : "=a"(aw[(q * 15 + m) * 4 + 2]) : "v"(v.z));
            asm volatile("v_accvgpr_write_b32 %0, %1" : "=a"(aw[(q * 15 + m) * 4 + 3]) : "v"(v.w));
        }
    }

    uint wihr[24];
    float bias[4];
    #pragma unroll
    for (int q = 0; q < 4; ++q) {
        #pragma unroll
        for (int dp = 0; dp < 6; ++dp)
            wihr[q * 6 + dp] = wih0p[((dir * 4 + q) * 6 + dp) * 256 + tid];
        bias[q] = b_ih0[dir * NG + q * 256 + tid] + b_hh0[dir * NG + q * 256 + tid];
    }

    const int sidx = (dir * NB + b) * NH + tid;
    float cv = 0.f, hv = 0.f;
    hs16[tid] = hbits((f16)0.f);
    __syncthreads();

    #pragma unroll 1
    for (int it = 0; it < NT; ++it) {
        const int par = it & 1;
        uint4 hvv = ((const uint4*)(hs16 + par * 256))[tid & 31];

        const int t = dir ? (NT - 1 - it) : it;
        const float4* xp = (const float4*)(x + ((size_t)b * NT + t) * DIN);
        float4 A = xp[0], B4 = xp[1], C4 = xp[2];
        float xv[12] = {A.x, A.y, A.z, A.w, B4.x, B4.y, B4.z, B4.w,
                        C4.x, C4.y, C4.z, C4.w};

        float ahA[4] = {0.f, 0.f, 0.f, 0.f};
        float ahB[4] = {0.f, 0.f, 0.f, 0.f};

        // ---- VGPR region: h chunks 0..9 ----
        #pragma unroll
        for (int g = 0; g < 10; ++g) {
            RDL4(hvv, g, s0, s1, s2, s3);
            DOTS_GRP(ahA, ahB, wrv[0][g], wrv[1][g], wrv[2][g], wrv[3][g],
                     s0, s1, s2, s3);
        }
        // ---- interleaved AGPR (m=0..14, chunks 10..24) + LDS (l=0..6, 25..31) ----
        #pragma unroll
        for (int l = 0; l < 7; ++l) {
            uint4 lw0 = wlds4[(0 * 7 + l) * 256 + tid];   // issue LDS reads early
            uint4 lw1 = wlds4[(1 * 7 + l) * 256 + tid];
            uint4 lw2 = wlds4[(2 * 7 + l) * 256 + tid];
            uint4 lw3 = wlds4[(3 * 7 + l) * 256 + tid];
            #pragma unroll
            for (int j = 0; j < 2; ++j) {                 // 2 AGPR groups of cover
                const int m = 2 * l + j;
                RDL4(hvv, 10 + m, s0, s1, s2, s3);
                AGPR_GRP(ahA, ahB, aw, m, s0, s1, s2, s3);
            }
            RDL4(hvv, 25 + l, t0, t1, t2, t3);
            DOTS_GRP(ahA, ahB, lw0, lw1, lw2, lw3, t0, t1, t2, t3);
        }
        {   // leftover AGPR group m=14 (chunk 24)
            RDL4(hvv, 24, s0, s1, s2, s3);
            AGPR_GRP(ahA, ahB, aw, 14, s0, s1, s2, s3);
        }

        // ---- input projection, comp-major across the 4 gate chains ----
        float zx0 = bias[0], zx1 = bias[1], zx2 = bias[2], zx3 = bias[3];
        #pragma unroll
        for (int d = 0; d < 6; ++d) {
            uint xph = pkrtz(xv[2 * d], xv[2 * d + 1]);
            zx0 = dot2(wihr[0 * 6 + d], xph, zx0);
            zx1 = dot2(wihr[1 * 6 + d], xph, zx1);
            zx2 = dot2(wihr[2 * 6 + d], xph, zx2);
            zx3 = dot2(wihr[3 * 6 + d], xph, zx3);
        }
        float z0 = ahA[0] + ahB[0] + zx0;
        float z1 = ahA[1] + ahB[1] + zx1;
        float z2 = ahA[2] + ahB[2] + zx2;
        float z3 = ahA[3] + ahB[3] + zx3;
        cv = sigm(z1) * cv + sigm(z0) * tanh_(z2);
        hv = sigm(z3) * tanh_(cv);

        f16 hi = (f16)hv;
        hs16[(par ^ 1) * 256 + tid] = hbits(hi);
        out0h[((size_t)b * NT + t) * 512 + dir * 256 + tid] = hi;
        __syncthreads();
    }

    cst[sidx] = cv; hst[sidx] = hv;
}

// ---------------------------------------------------------------------------
// rec1_seq: layer-1 recurrence, round-12. Switched from per-group LDS
// broadcast reads of h to the readlane scheme (1 b128 read + 128 readlanes):
// once chain stalls are removed, 32x ds_read latency would become the exposed
// wall; readlane keeps the broadcast on the short-latency VALU path.
// Weights: 192 VGPR + 240 AGPR uints + 80 KB LDS; LDS-weight groups
// interleaved between AGPR groups (3 of cover each). xq prefetched one step
// ahead. One barrier per step.
// ---------------------------------------------------------------------------
__device__ void rec1_seq(char* smem, int rb, int chunk, int nsteps,
                         const uint* __restrict__ Wkv1, const uint* __restrict__ Wka1,
                         const uint4* __restrict__ Wkl1, const float* __restrict__ xp1,
                         float* __restrict__ hst, float* __restrict__ cst,
                         float* __restrict__ hsm) {
    uint4* wlds4 = (uint4*)smem;                         // [4][5][256] uint4 = 80 KB
    ushort* hs16 = (ushort*)(smem + 81920);              // [2 par][256] f16 = 1 KB

    const int tid = threadIdx.x;
    const int dir = rb >> 6;
    const int b = rb & 63;
    const int ld = 2 + dir;

    for (int n = tid; n < 5120; n += 256) wlds4[n] = Wkl1[dir * 5120 + n];

    uint4 wrv[4][12];
    #pragma unroll
    for (int q = 0; q < 4; ++q) {
        const uint* src = Wkv1 + (size_t)((dir * 4 + q) * 256 + tid) * 48;
        #pragma unroll
        for (int m = 0; m < 12; ++m) wrv[q][m] = *(const uint4*)(src + m * 4);
    }

    uint aw[240];
    #pragma unroll
    for (int q = 0; q < 4; ++q) {
        const uint* src = Wka1 + (size_t)((dir * 4 + q) * 256 + tid) * 60;
        #pragma unroll
        for (int m = 0; m < 15; ++m) {
            uint4 v = *(const uint4*)(src + m * 4);
            asm volatile("v_accvgpr_write_b32 %0, %1" : "=a"(aw[(q * 15 + m) * 4 + 0]) : "v"(v.x));
            asm volatile("v_accvgpr_write_b32 %0, %1" : "=a"(aw[(q * 15 + m) * 4 + 1]) : "v"(v.y));
            asm volatile("v_accvgpr_write_b32 %0, %1" : "=a"(aw[(q * 15 + m) * 4 + 2]) : "v"(v.z));
            asm volatile("v_accvgpr_write_b32 %0, %1" : "=a"(aw[(q * 15 + m) * 4 + 3]) : "v"(v.w));
        }
    }

    const int sidx = (ld * NB + b) * NH + tid;
    float cv, hv, hsv = 0.f;
    if (chunk == 0) { cv = 0.f; hv = 0.f; }
    else {
        cv = cst[sidx]; hv = hst[sidx];
        hsv = hsm[(dir * NB + b) * NH + tid];
    }
    hs16[tid] = hbits((f16)hv);

    const float* xbase = xp1 + ((size_t)dir * NB + b) * TCL * NG + tid * 4;
    float4 xq_cur = *(const float4*)xbase;     // xq for step 0
    __syncthreads();

    #pragma unroll 1
    for (int it = 0; it < nsteps; ++it) {
        const int par = it & 1;
        uint4 hvv = ((const uint4*)(hs16 + par * 256))[tid & 31];

        // prefetch next step's gate inputs (full step of latency to hide)
        const int itn = (it + 1 < nsteps) ? (it + 1) : it;
        float4 xq_nxt = *(const float4*)(xbase + (size_t)itn * NG);

        float ahA[4] = {0.f, 0.f, 0.f, 0.f};
        float ahB[4] = {0.f, 0.f, 0.f, 0.f};

        // ---- VGPR region: h chunks 0..11 ----
        #pragma unroll
        for (int g = 0; g < 12; ++g) {
            RDL4(hvv, g, s0, s1, s2, s3);
            DOTS_GRP(ahA, ahB, wrv[0][g], wrv[1][g], wrv[2][g], wrv[3][g],
                     s0, s1, s2, s3);
        }
        // ---- interleaved AGPR (m=0..14, chunks 12..26) + LDS (l=0..4, 27..31) ----
        #pragma unroll
        for (int l = 0; l < 5; ++l) {
            uint4 lw0 = wlds4[(0 * 5 + l) * 256 + tid];   // issue LDS reads early
            uint4 lw1 = wlds4[(1 * 5 + l) * 256 + tid];
            uint4 lw2 = wlds4[(2 * 5 + l) * 256 + tid];
            uint4 lw3 = wlds4[(3 * 5 + l) * 256 + tid];
            #pragma unroll
            for (int j = 0; j < 3; ++j) {                 // 3 AGPR groups of cover
                const int m = 3 * l + j;
                RDL4(hvv, 12 + m, s0, s1, s2, s3);
                AGPR_GRP(ahA, ahB, aw, m, s0, s1, s2, s3);
            }
            RDL4(hvv, 27 + l, t0, t1, t2, t3);
            DOTS_GRP(ahA, ahB, lw0, lw1, lw2, lw3, t0, t1, t2, t3);
        }

        float z0 = ahA[0] + ahB[0] + xq_cur.x;
        float z1 = ahA[1] + ahB[1] + xq_cur.y;
        float z2 = ahA[2] + ahB[2] + xq_cur.z;
        float z3 = ahA[3] + ahB[3] + xq_cur.w;
        cv = sigm(z1) * cv + sigm(z0) * tanh_(z2);
        hv = sigm(z3) * tanh_(cv);
        hsv += hv;

        hs16[(par ^ 1) * 256 + tid] = hbits((f16)hv);
        __syncthreads();
        xq_cur = xq_nxt;
    }

    cst[sidx] = cv; hst[sidx] = hv;
    hsm[(dir * NB + b) * NH + tid] = hsv;
}

// ---------------------------------------------------------------------------
// proj_role (chunk c): fp16 MFMA 16x16x32 direct-from-global (layout verified
// rounds 6-11). 128 role-blocks x 4 waves; wave handles 2 m-tiles. Stores xp1
// as [t][unit][gate] so rec1's per-step fetch is one coalesced float4.
// ---------------------------------------------------------------------------
__device__ void proj_role(int pb, int c,
                          const f16* __restrict__ out0h, const f16* __restrict__ wih1h,
                          const float* __restrict__ bsum1, float* __restrict__ xp1) {
    const int tid = threadIdx.x;
    const int w = tid >> 6, l = tid & 63;
    const int lane16 = l & 15, quad = l >> 4;

    #pragma unroll 1
    for (int mi = 0; mi < 2; ++mi) {
        const int mtg = pb * 8 + w * 2 + mi;       // 0..1023
        const int dirt = mtg >> 9;
        const int mtl = mtg & 511;

        const int ra = mtl * 16 + lane16;          // row over b(64) x tl(128)
        const int ab = ra >> 7, tla = ra & 127;
        const int ta = dirt ? (NT - 1 - c * TCL - tla) : (c * TCL + tla);
        const f16* Arow = out0h + ((size_t)ab * NT + ta) * 512 + quad * 8;

        uint4 afr[16];
        #pragma unroll
        for (int kt = 0; kt < 16; ++kt) afr[kt] = *(const uint4*)(Arow + kt * 32);

        int ob[4], otl[4];
        #pragma unroll
        for (int reg = 0; reg < 4; ++reg) {
            int rr = mtl * 16 + quad * 4 + reg;
            ob[reg] = rr >> 7; otl[reg] = rr & 127;
        }

        const f16* Bbase = wih1h + (size_t)dirt * NG * 512 + quad * 8;

        #pragma unroll 1
        for (int nt = 0; nt < 64; ++nt) {
            const int col = nt * 16 + lane16;
            const f16* Brow = Bbase + (size_t)col * 512;
            float bias = bsum1[dirt * NG + col];

            f32x4 acc = {0.f, 0.f, 0.f, 0.f};
            #pragma unroll
            for (int kt = 0; kt < 16; ++kt) {
                uint4 bv = *(const uint4*)(Brow + kt * 32);
                acc = __builtin_amdgcn_mfma_f32_16x16x32_f16(
                    __builtin_bit_cast(f16x8, afr[kt]),
                    __builtin_bit_cast(f16x8, bv), acc, 0, 0, 0);
            }
            const int ucol = col & 255, qcol = col >> 8;
            #pragma unroll
            for (int reg = 0; reg < 4; ++reg) {
                xp1[((size_t)(dirt * NB + ob[reg]) * TCL + otl[reg]) * NG
                    + ucol * 4 + qcol] = acc[reg] + bias;
            }
        }
    }
}

// ---------------------------------------------------------------------------
// Phase A: layer 0, full 1024 steps, 128 independent blocks.
// ---------------------------------------------------------------------------
__global__ __launch_bounds__(256, 1) void k_rec0(
    const uint* __restrict__ Wkv0, const uint* __restrict__ Wka0,
    const uint4* __restrict__ Wkl0, const uint* __restrict__ wih0p,
    const float* __restrict__ b_ih0, const float* __restrict__ b_hh0,
    const float* __restrict__ x, f16* __restrict__ out0h,
    float* __restrict__ hst, float* __restrict__ cst) {
    extern __shared__ __align__(16) char smem[];
    rec0_seq(smem, blockIdx.x, Wkv0, Wka0, Wkl0, wih0p, b_ih0, b_hh0,
             x, out0h, hst, cst);
}

// ---------------------------------------------------------------------------
// Phase B launch j: blocks 0..127 = rec1 chunk j-1; blocks 128..255 = proj
// chunk j (legal: out0h complete after phase A). Double-buffered xp1.
// ---------------------------------------------------------------------------
__global__ __launch_bounds__(256, 1) void k_pipe(
    int j,
    const uint* __restrict__ Wkv1, const uint* __restrict__ Wka1,
    const uint4* __restrict__ Wkl1,
    const f16* __restrict__ out0h, const f16* __restrict__ wih1h,
    const float* __restrict__ bsum1, float* __restrict__ xp1,
    float* __restrict__ hst, float* __restrict__ cst, float* __restrict__ hsm) {
    extern __shared__ __align__(16) char smem[];
    const int bid = blockIdx.x;
    if (bid < 128) {
        const int cc = j - 1;
        if (cc >= 0 && cc < NCHUNK)
            rec1_seq(smem, bid, cc, TCL, Wkv1, Wka1, Wkl1,
                     xp1 + (size_t)(cc & 1) * XPS, hst, cst, hsm);
    } else {
        const int cp = j;
        if (cp < NCHUNK)
            proj_role(bid - 128, cp, out0h, wih1h, bsum1,
                      xp1 + (size_t)(cp & 1) * XPS);
    }
}

// ---------------------------------------------------------------------------
__global__ void k_fc(const float* __restrict__ hsm, const float* __restrict__ fc_w,
                     const float* __restrict__ fc_b, float* __restrict__ out) {
    const int b = blockIdx.x;
    const int n = threadIdx.x;
    if (n >= NCLS) return;
    float acc = fc_b[n];
    const float inv = 1.0f / (float)NT;
    for (int k = 0; k < 2 * NH; ++k) {
        float pv = hsm[((k >> 8) * NB + b) * NH + (k & 255)];
        acc += (pv * inv) * fc_w[n * 2 * NH + k];
    }
    out[b * NCLS + n] = acc;
}

// ---------------------------------------------------------------------------
extern "C" void kernel_launch(void* const* d_in, const int* in_sizes, int n_in,
                              void* d_out, int out_size, void* d_ws, size_t ws_size,
                              hipStream_t stream) {
    const float* x     = (const float*)d_in[0];
    const float* w_ih0 = (const float*)d_in[1];
    const float* w_hh0 = (const float*)d_in[2];
    const float* b_ih0 = (const float*)d_in[3];
    const float* b_hh0 = (const float*)d_in[4];
    const float* w_ih1 = (const float*)d_in[5];
    const float* w_hh1 = (const float*)d_in[6];
    const float* b_ih1 = (const float*)d_in[7];
    const float* b_hh1 = (const float*)d_in[8];
    const float* fc_w  = (const float*)d_in[9];
    const float* fc_b  = (const float*)d_in[10];
    float* out = (float*)d_out;

    char* ws = (char*)d_ws;
    uint* Wkv0  = (uint*)ws;                      // 81920 u
    uint* Wka0  = Wkv0 + 81920;                   // 122880 u
    uint* Wkl0  = Wka0 + 122880;                  // 57344 u
    uint* wih0p = Wkl0 + 57344;                   // 12288 u
    uint* Wkv1  = wih0p + 12288;                  // 98304 u
    uint* Wka1  = Wkv1 + 98304;                   // 122880 u
    uint* Wkl1  = Wka1 + 122880;                  // 40960 u
    f16* wih1h  = (f16*)(Wkl1 + 40960);           // 1048576 h = 2 MB
    float* bsum1 = (float*)(wih1h + 1048576);     // 2048 f
    float* hst  = bsum1 + 2048;                   // 65536 f
    float* cst  = hst + 65536;                    // 65536 f
    float* hsm  = cst + 65536;                    // 32768 f
    float* xp1  = hsm + 32768;                    // 2 x 16777216 f = 128 MB
    f16* out0h  = (f16*)(xp1 + 2 * XPS);          // 33554432 h = 64 MB

    k_prep<<<dim3(4096), dim3(256), 0, stream>>>(
        w_hh0, w_hh1, w_ih0, w_ih1, b_ih1, b_hh1,
        Wkv0, Wka0, Wkl0, wih0p, Wkv1, Wka1, Wkl1, wih1h, bsum1);

    k_rec0<<<dim3(128), dim3(256), 115712, stream>>>(
        Wkv0, Wka0, (const uint4*)Wkl0, wih0p, b_ih0, b_hh0, x, out0h, hst, cst);

    for (int j = 0; j <= NCHUNK; ++j) {
        k_pipe<<<dim3(256), dim3(256), 82944, stream>>>(
            j, Wkv1, Wka1, (const uint4*)Wkl1, out0h, wih1h, bsum1,
            xp1, hst, cst, hsm);
    }

    k_fc<<<dim3(64), dim3(32), 0, stream>>>(hsm, fc_w, fc_b, out);
}

// Round 2
// 4501.382 us; speedup vs baseline: 1.0384x; 1.0329x over previous
//
#include <hip/hip_runtime.h>

#define NB 64
#define NT 1024
#define DIN 12
#define NH 256
#define NG 1024
#define NCLS 17
#define TCL 128
#define NCHUNK 8
#define XPS ((size_t)2 * NB * TCL * NG)   // floats per xp1 chunk buffer

typedef _Float16 f16;
typedef __attribute__((ext_vector_type(2))) _Float16 half2_t;
typedef __attribute__((ext_vector_type(8))) _Float16 f16x8;
typedef __attribute__((ext_vector_type(4))) float f32x4;
typedef unsigned int uint;
typedef unsigned short ushort;

__device__ __forceinline__ float sigm(float v) { return 1.0f / (1.0f + __expf(-v)); }
__device__ __forceinline__ float tanh_(float v) {
    v = fminf(fmaxf(v, -15.0f), 15.0f);
    float e = __expf(2.0f * v);
    return (e - 1.0f) / (e + 1.0f);
}
__device__ __forceinline__ float dot2(uint w, uint h, float c) {
    return __builtin_amdgcn_fdot2(__builtin_bit_cast(half2_t, w),
                                  __builtin_bit_cast(half2_t, h), c, false);
}
__device__ __forceinline__ uint pack16(float a, float b) {
    union { f16 h[2]; uint u; } cv; cv.h[0] = (f16)a; cv.h[1] = (f16)b; return cv.u;
}
__device__ __forceinline__ uint pkrtz(float a, float b) {
    return __builtin_bit_cast(uint, __builtin_amdgcn_cvt_pkrtz(a, b));
}
__device__ __forceinline__ ushort hbits(f16 v) {
    union { f16 h; ushort u; } cv; cv.h = v; return cv.u;
}
__device__ __forceinline__ uint rdlane(uint v, int l) {
    return (uint)__builtin_amdgcn_readlane((int)v, l);
}

// ---------------------------------------------------------------------------
// Interleave machinery (comp-major over 8 accumulators).
// ---------------------------------------------------------------------------
#define RDL4(HV, G, S0, S1, S2, S3)                                           \
    uint S0 = rdlane((HV).x, (G)), S1 = rdlane((HV).y, (G)),                  \
         S2 = rdlane((HV).z, (G)), S3 = rdlane((HV).w, (G))

#define DOTS_GRP(AH, BH, W0, W1, W2, W3, S0, S1, S2, S3) do {                 \
    AH[0] = dot2((W0).x, (S0), AH[0]); AH[1] = dot2((W1).x, (S0), AH[1]);     \
    AH[2] = dot2((W2).x, (S0), AH[2]); AH[3] = dot2((W3).x, (S0), AH[3]);     \
    BH[0] = dot2((W0).y, (S1), BH[0]); BH[1] = dot2((W1).y, (S1), BH[1]);     \
    BH[2] = dot2((W2).y, (S1), BH[2]); BH[3] = dot2((W3).y, (S1), BH[3]);     \
    AH[0] = dot2((W0).z, (S2), AH[0]); AH[1] = dot2((W1).z, (S2), AH[1]);     \
    AH[2] = dot2((W2).z, (S2), AH[2]); AH[3] = dot2((W3).z, (S2), AH[3]);     \
    BH[0] = dot2((W0).w, (S3), BH[0]); BH[1] = dot2((W1).w, (S3), BH[1]);     \
    BH[2] = dot2((W2).w, (S3), BH[2]); BH[3] = dot2((W3).w, (S3), BH[3]);     \
} while (0)

// AGPR-weight group (still used by rec1).
#define AGPR_GRP(AH, BH, AW, M, S0, S1, S2, S3) do {                          \
    uint w0_, w1_, w2_, w3_;                                                  \
    asm volatile("v_accvgpr_read_b32 %0, %1" : "=v"(w0_) : "a"(AW[(0*15+(M))*4+0])); \
    asm volatile("v_accvgpr_read_b32 %0, %1" : "=v"(w1_) : "a"(AW[(1*15+(M))*4+0])); \
    asm volatile("v_accvgpr_read_b32 %0, %1" : "=v"(w2_) : "a"(AW[(2*15+(M))*4+0])); \
    asm volatile("v_accvgpr_read_b32 %0, %1" : "=v"(w3_) : "a"(AW[(3*15+(M))*4+0])); \
    AH[0] = dot2(w0_, (S0), AH[0]); AH[1] = dot2(w1_, (S0), AH[1]);           \
    AH[2] = dot2(w2_, (S0), AH[2]); AH[3] = dot2(w3_, (S0), AH[3]);           \
    asm volatile("v_accvgpr_read_b32 %0, %1" : "=v"(w0_) : "a"(AW[(0*15+(M))*4+1])); \
    asm volatile("v_accvgpr_read_b32 %0, %1" : "=v"(w1_) : "a"(AW[(1*15+(M))*4+1])); \
    asm volatile("v_accvgpr_read_b32 %0, %1" : "=v"(w2_) : "a"(AW[(2*15+(M))*4+1])); \
    asm volatile("v_accvgpr_read_b32 %0, %1" : "=v"(w3_) : "a"(AW[(3*15+(M))*4+1])); \
    BH[0] = dot2(w0_, (S1), BH[0]); BH[1] = dot2(w1_, (S1), BH[1]);           \
    BH[2] = dot2(w2_, (S1), BH[2]); BH[3] = dot2(w3_, (S1), BH[3]);           \
    asm volatile("v_accvgpr_read_b32 %0, %1" : "=v"(w0_) : "a"(AW[(0*15+(M))*4+2])); \
    asm volatile("v_accvgpr_read_b32 %0, %1" : "=v"(w1_) : "a"(AW[(1*15+(M))*4+2])); \
    asm volatile("v_accvgpr_read_b32 %0, %1" : "=v"(w2_) : "a"(AW[(2*15+(M))*4+2])); \
    asm volatile("v_accvgpr_read_b32 %0, %1" : "=v"(w3_) : "a"(AW[(3*15+(M))*4+2])); \
    AH[0] = dot2(w0_, (S2), AH[0]); AH[1] = dot2(w1_, (S2), AH[1]);           \
    AH[2] = dot2(w2_, (S2), AH[2]); AH[3] = dot2(w3_, (S2), AH[3]);           \
    asm volatile("v_accvgpr_read_b32 %0, %1" : "=v"(w0_) : "a"(AW[(0*15+(M))*4+3])); \
    asm volatile("v_accvgpr_read_b32 %0, %1" : "=v"(w1_) : "a"(AW[(1*15+(M))*4+3])); \
    asm volatile("v_accvgpr_read_b32 %0, %1" : "=v"(w2_) : "a"(AW[(2*15+(M))*4+3])); \
    asm volatile("v_accvgpr_read_b32 %0, %1" : "=v"(w3_) : "a"(AW[(3*15+(M))*4+3])); \
    BH[0] = dot2(w0_, (S3), BH[0]); BH[1] = dot2(w1_, (S3), BH[1]);           \
    BH[2] = dot2(w2_, (S3), BH[2]); BH[3] = dot2(w3_, (S3), BH[3]);           \
} while (0)

// ---------------------------------------------------------------------------
// k_prep. Layer 0 now packed for the round-12 k-split rec0 (512 threads,
// lane = (unit u, k-half kh)): Wk0n [dir][q][m 0..15][t512] uint4, where
// uint4 #m of lane t512 holds kp pairs {kh*64+4m+c}. wih0n holds the 2
// input-proj gate rows owned by each lane (q = 2*kh+g2).
// Layer-1 buffers unchanged.
// ---------------------------------------------------------------------------
__global__ void k_prep(const float* __restrict__ w_hh0, const float* __restrict__ w_hh1,
                       const float* __restrict__ w_ih0, const float* __restrict__ w_ih1,
                       const float* __restrict__ b_ih1, const float* __restrict__ b_hh1,
                       uint* __restrict__ Wk0n, uint* __restrict__ wih0n,
                       uint* __restrict__ Wkv1, uint* __restrict__ Wka1,
                       uint* __restrict__ Wkl1,
                       f16* __restrict__ wih1h, float* __restrict__ bsum1) {
    int i = blockIdx.x * 256 + threadIdx.x;
    // ---- layer 0 (k-split packing) ----
    if (i < 262144) {                      // Wk0n
        int c = i & 3; int r = i >> 2;
        int t512 = r & 511; int s = r >> 9;
        int m = s & 15, q = (s >> 4) & 3, dir = s >> 6;
        int u = t512 & 255, kh = t512 >> 8;
        int kp = kh * 64 + 4 * m + c;
        const float* row = w_hh0 + (size_t)dir * NG * NH + (size_t)(q * 256 + u) * NH;
        Wk0n[i] = pack16(row[2 * kp], row[2 * kp + 1]);
    }
    if (i < 12288) {                       // wih0n: [dir][g2*6+dp][t512]
        int t512 = i & 511; int r = i >> 9;
        int dp = r % 6, g2 = (r / 6) & 1, dir = r / 12;
        int q = 2 * (t512 >> 8) + g2, u = t512 & 255;
        const float* row = w_ih0 + ((size_t)dir * NG + q * 256 + u) * DIN;
        wih0n[i] = pack16(row[2 * dp], row[2 * dp + 1]);
    }
    // ---- layer 1 (unchanged) ----
    if (i < 2 * 4 * 256 * 48) {            // Wkv1
        int kp = i % 48; int r = i / 48;
        int t = r & 255, q = (r >> 8) & 3, dir = r >> 10;
        const float* row = w_hh1 + (size_t)dir * NG * NH + (size_t)(q * 256 + t) * NH;
        Wkv1[i] = pack16(row[2 * kp], row[2 * kp + 1]);
    }
    if (i < 2 * 4 * 256 * 60) {            // Wka1 (kp 48..107)
        int kp = 48 + (i % 60); int r = i / 60;
        int t = r & 255, q = (r >> 8) & 3, dir = r >> 10;
        const float* row = w_hh1 + (size_t)dir * NG * NH + (size_t)(q * 256 + t) * NH;
        Wka1[i] = pack16(row[2 * kp], row[2 * kp + 1]);
    }
    if (i < 2 * 4 * 5 * 256 * 4) {         // Wkl1 (kp 108..127)
        int j = i & 3; int u = i >> 2;
        int t = u & 255; int v = u >> 8;
        int g = v % 5; int w2 = v / 5;
        int q = w2 & 3, dir = w2 >> 2;
        int kp = 108 + 4 * g + j;
        const float* row = w_hh1 + (size_t)dir * NG * NH + (size_t)(q * 256 + t) * NH;
        Wkl1[i] = pack16(row[2 * kp], row[2 * kp + 1]);
    }
    if (i < 2 * NG * 2 * NH) wih1h[i] = (f16)w_ih1[i];
    if (i < 2 * NG) bsum1[i] = b_ih1[i] + b_hh1[i];
}

// ---------------------------------------------------------------------------
// rec0_seq (round 12): k-split, 512 threads = 8 waves = 2 waves/SIMD.
// Lane (u = tid&255, kh = tid>>8) computes partial pre-activations for all 4
// gates of unit u over kp in [kh*64, kh*64+64). Weights: 48 uint4 in regs
// (g 0..11) + 16 uint4 in LDS (g 12..15) => ~240 regs/wave, 2 waves/SIMD.
// Partials combined via 4 KB LDS exchange; kh=0 lanes own the cell state.
// Two barriers/step. The second resident wave per SIMD hides the per-wave
// stalls that pinned VALUBusy at ~40% with 1 wave/SIMD.
// ---------------------------------------------------------------------------
__device__ void rec0_seq(char* smem, int rb,
                         const uint* __restrict__ Wk0n, const uint* __restrict__ wih0n,
                         const float* __restrict__ b_ih0, const float* __restrict__ b_hh0,
                         const float* __restrict__ x, f16* __restrict__ out0h,
                         float* __restrict__ hst, float* __restrict__ cst) {
    uint4* wlds4 = (uint4*)smem;                         // [4 q][4 mm][512] uint4 = 128 KB
    ushort* hs16 = (ushort*)(smem + 131072);             // [2 par][256] f16 = 1 KB
    float4* zb4  = (float4*)(smem + 132096);             // [256] float4 = 4 KB

    const int tid = threadIdx.x;
    const int dir = rb >> 6;
    const int b = rb & 63;
    const int u = tid & 255;
    const int kh = tid >> 8;
    const uint4* W4 = (const uint4*)Wk0n;

    #pragma unroll
    for (int q = 0; q < 4; ++q)
        #pragma unroll
        for (int mm = 0; mm < 4; ++mm)
            wlds4[(q * 4 + mm) * 512 + tid] =
                W4[((size_t)(dir * 4 + q) * 16 + 12 + mm) * 512 + tid];

    uint4 wr[4][12];
    #pragma unroll
    for (int q = 0; q < 4; ++q)
        #pragma unroll
        for (int m = 0; m < 12; ++m)
            wr[q][m] = W4[((size_t)(dir * 4 + q) * 16 + m) * 512 + tid];

    uint wih[12];
    float bias2[2];
    #pragma unroll
    for (int g2 = 0; g2 < 2; ++g2) {
        const int q = 2 * kh + g2;
        bias2[g2] = b_ih0[dir * NG + q * 256 + u] + b_hh0[dir * NG + q * 256 + u];
        #pragma unroll
        for (int dp = 0; dp < 6; ++dp)
            wih[g2 * 6 + dp] = wih0n[(dir * 12 + g2 * 6 + dp) * 512 + tid];
    }

    const int sidx = (dir * NB + b) * NH + u;
    float cv = 0.f, hv = 0.f;
    if (tid < 256) hs16[tid] = 0;
    __syncthreads();

    #pragma unroll 1
    for (int it = 0; it < NT; ++it) {
        const int par = it & 1;
        uint4 hvv = ((const uint4*)(hs16 + par * 256))[kh * 16 + (tid & 15)];

        const int t = dir ? (NT - 1 - it) : it;
        const float4* xp = (const float4*)(x + ((size_t)b * NT + t) * DIN);
        float4 A = xp[0], B4 = xp[1], C4 = xp[2];
        uint xph[6] = {pkrtz(A.x, A.y), pkrtz(A.z, A.w), pkrtz(B4.x, B4.y),
                       pkrtz(B4.z, B4.w), pkrtz(C4.x, C4.y), pkrtz(C4.z, C4.w)};

        float ahA[4] = {0.f, 0.f, 0.f, 0.f};
        float ahB[4] = {0.f, 0.f, 0.f, 0.f};

        // ---- register groups g = 0..11 (kp kh*64 + 0..47) ----
        #pragma unroll
        for (int g = 0; g < 12; ++g) {
            RDL4(hvv, g, s0, s1, s2, s3);
            DOTS_GRP(ahA, ahB, wr[0][g], wr[1][g], wr[2][g], wr[3][g],
                     s0, s1, s2, s3);
        }
        // ---- LDS groups g = 12..15 (kp kh*64 + 48..63) ----
        #pragma unroll
        for (int gg = 0; gg < 4; ++gg) {
            uint4 l0 = wlds4[(0 * 4 + gg) * 512 + tid];
            uint4 l1 = wlds4[(1 * 4 + gg) * 512 + tid];
            uint4 l2 = wlds4[(2 * 4 + gg) * 512 + tid];
            uint4 l3 = wlds4[(3 * 4 + gg) * 512 + tid];
            RDL4(hvv, 12 + gg, s0, s1, s2, s3);
            DOTS_GRP(ahA, ahB, l0, l1, l2, l3, s0, s1, s2, s3);
        }

        // ---- input projection for this lane's 2 owned gates ----
        float xz0 = bias2[0], xz1 = bias2[1];
        #pragma unroll
        for (int d = 0; d < 6; ++d) {
            xz0 = dot2(wih[d], xph[d], xz0);
            xz1 = dot2(wih[6 + d], xph[d], xz1);
        }

        float p0 = ahA[0] + ahB[0], p1 = ahA[1] + ahB[1];
        float p2 = ahA[2] + ahB[2], p3 = ahA[3] + ahB[3];
        if (kh == 0) { p0 += xz0; p1 += xz1; }   // kh uniform per wave: no divergence
        else         { p2 += xz0; p3 += xz1; }

        if (kh) zb4[u] = (float4){p0, p1, p2, p3};
        __syncthreads();                          // A: partials visible
        if (!kh) {
            float4 zp = zb4[u];
            float z0 = p0 + zp.x, z1 = p1 + zp.y;
            float z2 = p2 + zp.z, z3 = p3 + zp.w;
            cv = sigm(z1) * cv + sigm(z0) * tanh_(z2);
            hv = sigm(z3) * tanh_(cv);
            f16 hi = (f16)hv;
            hs16[(par ^ 1) * 256 + u] = hbits(hi);
            out0h[((size_t)b * NT + t) * 512 + dir * 256 + u] = hi;
        }
        __syncthreads();                          // B: new h visible
    }

    if (!kh) { cst[sidx] = cv; hst[sidx] = hv; }
}

// ---------------------------------------------------------------------------
// rec1_seq: unchanged from round 11/12 (256 threads, 1 wave/SIMD).
// Port to the k-split structure next round if rec0 confirms the TLP theory.
// ---------------------------------------------------------------------------
__device__ void rec1_seq(char* smem, int rb, int chunk, int nsteps,
                         const uint* __restrict__ Wkv1, const uint* __restrict__ Wka1,
                         const uint4* __restrict__ Wkl1, const float* __restrict__ xp1,
                         float* __restrict__ hst, float* __restrict__ cst,
                         float* __restrict__ hsm) {
    uint4* wlds4 = (uint4*)smem;                         // [4][5][256] uint4 = 80 KB
    ushort* hs16 = (ushort*)(smem + 81920);              // [2 par][256] f16 = 1 KB

    const int tid = threadIdx.x;
    const int dir = rb >> 6;
    const int b = rb & 63;
    const int ld = 2 + dir;

    for (int n = tid; n < 5120; n += 256) wlds4[n] = Wkl1[dir * 5120 + n];

    uint4 wrv[4][12];
    #pragma unroll
    for (int q = 0; q < 4; ++q) {
        const uint* src = Wkv1 + (size_t)((dir * 4 + q) * 256 + tid) * 48;
        #pragma unroll
        for (int m = 0; m < 12; ++m) wrv[q][m] = *(const uint4*)(src + m * 4);
    }

    uint aw[240];
    #pragma unroll
    for (int q = 0; q < 4; ++q) {
        const uint* src = Wka1 + (size_t)((dir * 4 + q) * 256 + tid) * 60;
        #pragma unroll
        for (int m = 0; m < 15; ++m) {
            uint4 v = *(const uint4*)(src + m * 4);
            asm volatile("v_accvgpr_write_b32 %0, %1" : "=a"(aw[(q * 15 + m) * 4 + 0]) : "v"(v.x));
            asm volatile("v_accvgpr_write_b32 %0, %1" : "=a"(aw[(q * 15 + m) * 4 + 1]) : "v"(v.y));
            asm volatile("v_accvgpr_write_b32 %0, %1" : "=a"(aw[(q * 15 + m) * 4 + 2]) : "v"(v.z));
            asm volatile("v_accvgpr_write_b32 %0, %1" : "=a"(aw[(q * 15 + m) * 4 + 3]) : "v"(v.w));
        }
    }

    const int sidx = (ld * NB + b) * NH + tid;
    float cv, hv, hsv = 0.f;
    if (chunk == 0) { cv = 0.f; hv = 0.f; }
    else {
        cv = cst[sidx]; hv = hst[sidx];
        hsv = hsm[(dir * NB + b) * NH + tid];
    }
    hs16[tid] = hbits((f16)hv);

    const float* xbase = xp1 + ((size_t)dir * NB + b) * TCL * NG + tid * 4;
    float4 xq_cur = *(const float4*)xbase;     // xq for step 0
    __syncthreads();

    #pragma unroll 1
    for (int it = 0; it < nsteps; ++it) {
        const int par = it & 1;
        uint4 hvv = ((const uint4*)(hs16 + par * 256))[tid & 31];

        // prefetch next step's gate inputs (full step of latency to hide)
        const int itn = (it + 1 < nsteps) ? (it + 1) : it;
        float4 xq_nxt = *(const float4*)(xbase + (size_t)itn * NG);

        float ahA[4] = {0.f, 0.f, 0.f, 0.f};
        float ahB[4] = {0.f, 0.f, 0.f, 0.f};

        // ---- VGPR region: h chunks 0..11 ----
        #pragma unroll
        for (int g = 0; g < 12; ++g) {
            RDL4(hvv, g, s0, s1, s2, s3);
            DOTS_GRP(ahA, ahB, wrv[0][g], wrv[1][g], wrv[2][g], wrv[3][g],
                     s0, s1, s2, s3);
        }
        // ---- interleaved AGPR (m=0..14, chunks 12..26) + LDS (l=0..4, 27..31) ----
        #pragma unroll
        for (int l = 0; l < 5; ++l) {
            uint4 lw0 = wlds4[(0 * 5 + l) * 256 + tid];
            uint4 lw1 = wlds4[(1 * 5 + l) * 256 + tid];
            uint4 lw2 = wlds4[(2 * 5 + l) * 256 + tid];
            uint4 lw3 = wlds4[(3 * 5 + l) * 256 + tid];
            #pragma unroll
            for (int j = 0; j < 3; ++j) {
                const int m = 3 * l + j;
                RDL4(hvv, 12 + m, s0, s1, s2, s3);
                AGPR_GRP(ahA, ahB, aw, m, s0, s1, s2, s3);
            }
            RDL4(hvv, 27 + l, t0, t1, t2, t3);
            DOTS_GRP(ahA, ahB, lw0, lw1, lw2, lw3, t0, t1, t2, t3);
        }

        float z0 = ahA[0] + ahB[0] + xq_cur.x;
        float z1 = ahA[1] + ahB[1] + xq_cur.y;
        float z2 = ahA[2] + ahB[2] + xq_cur.z;
        float z3 = ahA[3] + ahB[3] + xq_cur.w;
        cv = sigm(z1) * cv + sigm(z0) * tanh_(z2);
        hv = sigm(z3) * tanh_(cv);
        hsv += hv;

        hs16[(par ^ 1) * 256 + tid] = hbits((f16)hv);
        __syncthreads();
        xq_cur = xq_nxt;
    }

    cst[sidx] = cv; hst[sidx] = hv;
    hsm[(dir * NB + b) * NH + tid] = hsv;
}

// ---------------------------------------------------------------------------
// proj_role (chunk c): unchanged.
// ---------------------------------------------------------------------------
__device__ void proj_role(int pb, int c,
                          const f16* __restrict__ out0h, const f16* __restrict__ wih1h,
                          const float* __restrict__ bsum1, float* __restrict__ xp1) {
    const int tid = threadIdx.x;
    const int w = tid >> 6, l = tid & 63;
    const int lane16 = l & 15, quad = l >> 4;

    #pragma unroll 1
    for (int mi = 0; mi < 2; ++mi) {
        const int mtg = pb * 8 + w * 2 + mi;       // 0..1023
        const int dirt = mtg >> 9;
        const int mtl = mtg & 511;

        const int ra = mtl * 16 + lane16;          // row over b(64) x tl(128)
        const int ab = ra >> 7, tla = ra & 127;
        const int ta = dirt ? (NT - 1 - c * TCL - tla) : (c * TCL + tla);
        const f16* Arow = out0h + ((size_t)ab * NT + ta) * 512 + quad * 8;

        uint4 afr[16];
        #pragma unroll
        for (int kt = 0; kt < 16; ++kt) afr[kt] = *(const uint4*)(Arow + kt * 32);

        int ob[4], otl[4];
        #pragma unroll
        for (int reg = 0; reg < 4; ++reg) {
            int rr = mtl * 16 + quad * 4 + reg;
            ob[reg] = rr >> 7; otl[reg] = rr & 127;
        }

        const f16* Bbase = wih1h + (size_t)dirt * NG * 512 + quad * 8;

        #pragma unroll 1
        for (int nt = 0; nt < 64; ++nt) {
            const int col = nt * 16 + lane16;
            const f16* Brow = Bbase + (size_t)col * 512;
            float bias = bsum1[dirt * NG + col];

            f32x4 acc = {0.f, 0.f, 0.f, 0.f};
            #pragma unroll
            for (int kt = 0; kt < 16; ++kt) {
                uint4 bv = *(const uint4*)(Brow + kt * 32);
                acc = __builtin_amdgcn_mfma_f32_16x16x32_f16(
                    __builtin_bit_cast(f16x8, afr[kt]),
                    __builtin_bit_cast(f16x8, bv), acc, 0, 0, 0);
            }
            const int ucol = col & 255, qcol = col >> 8;
            #pragma unroll
            for (int reg = 0; reg < 4; ++reg) {
                xp1[((size_t)(dirt * NB + ob[reg]) * TCL + otl[reg]) * NG
                    + ucol * 4 + qcol] = acc[reg] + bias;
            }
        }
    }
}

// ---------------------------------------------------------------------------
// Phase A: layer 0, full 1024 steps, 128 blocks x 512 threads (2 waves/SIMD).
// ---------------------------------------------------------------------------
__global__ __launch_bounds__(512, 2) void k_rec0(
    const uint* __restrict__ Wk0n, const uint* __restrict__ wih0n,
    const float* __restrict__ b_ih0, const float* __restrict__ b_hh0,
    const float* __restrict__ x, f16* __restrict__ out0h,
    float* __restrict__ hst, float* __restrict__ cst) {
    extern __shared__ __align__(16) char smem[];
    rec0_seq(smem, blockIdx.x, Wk0n, wih0n, b_ih0, b_hh0, x, out0h, hst, cst);
}

// ---------------------------------------------------------------------------
// Phase B launch j: blocks 0..127 = rec1 chunk j-1; blocks 128..255 = proj
// chunk j. Unchanged.
// ---------------------------------------------------------------------------
__global__ __launch_bounds__(256, 1) void k_pipe(
    int j,
    const uint* __restrict__ Wkv1, const uint* __restrict__ Wka1,
    const uint4* __restrict__ Wkl1,
    const f16* __restrict__ out0h, const f16* __restrict__ wih1h,
    const float* __restrict__ bsum1, float* __restrict__ xp1,
    float* __restrict__ hst, float* __restrict__ cst, float* __restrict__ hsm) {
    extern __shared__ __align__(16) char smem[];
    const int bid = blockIdx.x;
    if (bid < 128) {
        const int cc = j - 1;
        if (cc >= 0 && cc < NCHUNK)
            rec1_seq(smem, bid, cc, TCL, Wkv1, Wka1, Wkl1,
                     xp1 + (size_t)(cc & 1) * XPS, hst, cst, hsm);
    } else {
        const int cp = j;
        if (cp < NCHUNK)
            proj_role(bid - 128, cp, out0h, wih1h, bsum1,
                      xp1 + (size_t)(cp & 1) * XPS);
    }
}

// ---------------------------------------------------------------------------
__global__ void k_fc(const float* __restrict__ hsm, const float* __restrict__ fc_w,
                     const float* __restrict__ fc_b, float* __restrict__ out) {
    const int b = blockIdx.x;
    const int n = threadIdx.x;
    if (n >= NCLS) return;
    float acc = fc_b[n];
    const float inv = 1.0f / (float)NT;
    for (int k = 0; k < 2 * NH; ++k) {
        float pv = hsm[((k >> 8) * NB + b) * NH + (k & 255)];
        acc += (pv * inv) * fc_w[n * 2 * NH + k];
    }
    out[b * NCLS + n] = acc;
}

// ---------------------------------------------------------------------------
extern "C" void kernel_launch(void* const* d_in, const int* in_sizes, int n_in,
                              void* d_out, int out_size, void* d_ws, size_t ws_size,
                              hipStream_t stream) {
    const float* x     = (const float*)d_in[0];
    const float* w_ih0 = (const float*)d_in[1];
    const float* w_hh0 = (const float*)d_in[2];
    const float* b_ih0 = (const float*)d_in[3];
    const float* b_hh0 = (const float*)d_in[4];
    const float* w_ih1 = (const float*)d_in[5];
    const float* w_hh1 = (const float*)d_in[6];
    const float* b_ih1 = (const float*)d_in[7];
    const float* b_hh1 = (const float*)d_in[8];
    const float* fc_w  = (const float*)d_in[9];
    const float* fc_b  = (const float*)d_in[10];
    float* out = (float*)d_out;

    char* ws = (char*)d_ws;
    uint* Wk0n  = (uint*)ws;                      // 262144 u
    uint* wih0n = Wk0n + 262144;                  // 12288 u
    uint* Wkv1  = wih0n + 12288;                  // 98304 u (offset 274432, as before)
    uint* Wka1  = Wkv1 + 98304;                   // 122880 u
    uint* Wkl1  = Wka1 + 122880;                  // 40960 u
    f16* wih1h  = (f16*)(Wkl1 + 40960);           // 1048576 h = 2 MB
    float* bsum1 = (float*)(wih1h + 1048576);     // 2048 f
    float* hst  = bsum1 + 2048;                   // 65536 f
    float* cst  = hst + 65536;                    // 65536 f
    float* hsm  = cst + 65536;                    // 32768 f
    float* xp1  = hsm + 32768;                    // 2 x 16777216 f = 128 MB
    f16* out0h  = (f16*)(xp1 + 2 * XPS);          // 33554432 h = 64 MB

    k_prep<<<dim3(4096), dim3(256), 0, stream>>>(
        w_hh0, w_hh1, w_ih0, w_ih1, b_ih1, b_hh1,
        Wk0n, wih0n, Wkv1, Wka1, Wkl1, wih1h, bsum1);

    k_rec0<<<dim3(128), dim3(512), 136192, stream>>>(
        Wk0n, wih0n, b_ih0, b_hh0, x, out0h, hst, cst);

    for (int j = 0; j <= NCHUNK; ++j) {
        k_pipe<<<dim3(256), dim3(256), 82944, stream>>>(
            j, Wkv1, Wka1, (const uint4*)Wkl1, out0h, wih1h, bsum1,
            xp1, hst, cst, hsm);
    }

    k_fc<<<dim3(64), dim3(32), 0, stream>>>(hsm, fc_w, fc_b, out);
}

// Round 3
// 4286.626 us; speedup vs baseline: 1.0904x; 1.0501x over previous
//
#include <hip/hip_runtime.h>

#define NB 64
#define NT 1024
#define DIN 12
#define NH 256
#define NG 1024
#define NCLS 17
#define TCL 128
#define NCHUNK 8
#define XPS ((size_t)2 * NB * TCL * NG)   // floats per xp1 chunk buffer

typedef _Float16 f16;
typedef __attribute__((ext_vector_type(2))) _Float16 half2_t;
typedef __attribute__((ext_vector_type(8))) _Float16 f16x8;
typedef __attribute__((ext_vector_type(4))) float f32x4;
typedef unsigned int uint;
typedef unsigned short ushort;

__device__ __forceinline__ float sigm(float v) { return 1.0f / (1.0f + __expf(-v)); }
__device__ __forceinline__ float tanh_(float v) {
    v = fminf(fmaxf(v, -15.0f), 15.0f);
    float e = __expf(2.0f * v);
    return (e - 1.0f) / (e + 1.0f);
}
__device__ __forceinline__ float dot2(uint w, uint h, float c) {
    return __builtin_amdgcn_fdot2(__builtin_bit_cast(half2_t, w),
                                  __builtin_bit_cast(half2_t, h), c, false);
}
__device__ __forceinline__ uint pack16(float a, float b) {
    union { f16 h[2]; uint u; } cv; cv.h[0] = (f16)a; cv.h[1] = (f16)b; return cv.u;
}
__device__ __forceinline__ uint pkrtz(float a, float b) {
    return __builtin_bit_cast(uint, __builtin_amdgcn_cvt_pkrtz(a, b));
}
__device__ __forceinline__ ushort hbits(f16 v) {
    union { f16 h; ushort u; } cv; cv.h = v; return cv.u;
}
__device__ __forceinline__ uint rdlane(uint v, int l) {
    return (uint)__builtin_amdgcn_readlane((int)v, l);
}

// ---------------------------------------------------------------------------
// Comp-major interleave over 8 accumulators.
// ---------------------------------------------------------------------------
#define RDL4(HV, G, S0, S1, S2, S3)                                           \
    uint S0 = rdlane((HV).x, (G)), S1 = rdlane((HV).y, (G)),                  \
         S2 = rdlane((HV).z, (G)), S3 = rdlane((HV).w, (G))

#define DOTS_GRP(AH, BH, W0, W1, W2, W3, S0, S1, S2, S3) do {                 \
    AH[0] = dot2((W0).x, (S0), AH[0]); AH[1] = dot2((W1).x, (S0), AH[1]);     \
    AH[2] = dot2((W2).x, (S0), AH[2]); AH[3] = dot2((W3).x, (S0), AH[3]);     \
    BH[0] = dot2((W0).y, (S1), BH[0]); BH[1] = dot2((W1).y, (S1), BH[1]);     \
    BH[2] = dot2((W2).y, (S1), BH[2]); BH[3] = dot2((W3).y, (S1), BH[3]);     \
    AH[0] = dot2((W0).z, (S2), AH[0]); AH[1] = dot2((W1).z, (S2), AH[1]);     \
    AH[2] = dot2((W2).z, (S2), AH[2]); AH[3] = dot2((W3).z, (S2), AH[3]);     \
    BH[0] = dot2((W0).w, (S3), BH[0]); BH[1] = dot2((W1).w, (S3), BH[1]);     \
    BH[2] = dot2((W2).w, (S3), BH[2]); BH[3] = dot2((W3).w, (S3), BH[3]);     \
} while (0)

// ---------------------------------------------------------------------------
// k_prep: unified k-split packing for BOTH recurrence layers.
// Wk{0,1}n [dir][q][m 0..15][t512] uint4: uint4 #m of lane t512=(u,kh) holds
// w_hh[dir][q*256+u][2*kp..2*kp+1] for kp = kh*64+4m+c, c=0..3.
// wih0n: rec0 input-proj pairs, lane-owned gates q=2*kh+g2.
// wih1h fp16 copy of w_ih1 (proj MFMA B); bsum1 = b_ih1 + b_hh1.
// ---------------------------------------------------------------------------
__global__ void k_prep(const float* __restrict__ w_hh0, const float* __restrict__ w_hh1,
                       const float* __restrict__ w_ih0, const float* __restrict__ w_ih1,
                       const float* __restrict__ b_ih1, const float* __restrict__ b_hh1,
                       uint* __restrict__ Wk0n, uint* __restrict__ wih0n,
                       uint* __restrict__ Wk1n,
                       f16* __restrict__ wih1h, float* __restrict__ bsum1) {
    int i = blockIdx.x * 256 + threadIdx.x;
    if (i < 262144) {                      // Wk0n
        int c = i & 3; int r = i >> 2;
        int t512 = r & 511; int s = r >> 9;
        int m = s & 15, q = (s >> 4) & 3, dir = s >> 6;
        int u = t512 & 255, kh = t512 >> 8;
        int kp = kh * 64 + 4 * m + c;
        const float* row = w_hh0 + (size_t)dir * NG * NH + (size_t)(q * 256 + u) * NH;
        Wk0n[i] = pack16(row[2 * kp], row[2 * kp + 1]);
    }
    if (i < 262144) {                      // Wk1n (same layout, layer 1)
        int c = i & 3; int r = i >> 2;
        int t512 = r & 511; int s = r >> 9;
        int m = s & 15, q = (s >> 4) & 3, dir = s >> 6;
        int u = t512 & 255, kh = t512 >> 8;
        int kp = kh * 64 + 4 * m + c;
        const float* row = w_hh1 + (size_t)dir * NG * NH + (size_t)(q * 256 + u) * NH;
        Wk1n[i] = pack16(row[2 * kp], row[2 * kp + 1]);
    }
    if (i < 12288) {                       // wih0n: [dir][g2*6+dp][t512]
        int t512 = i & 511; int r = i >> 9;
        int dp = r % 6, g2 = (r / 6) & 1, dir = r / 12;
        int q = 2 * (t512 >> 8) + g2, u = t512 & 255;
        const float* row = w_ih0 + ((size_t)dir * NG + q * 256 + u) * DIN;
        wih0n[i] = pack16(row[2 * dp], row[2 * dp + 1]);
    }
    if (i < 2 * NG * 2 * NH) wih1h[i] = (f16)w_ih1[i];
    if (i < 2 * NG) bsum1[i] = b_ih1[i] + b_hh1[i];
}

// ---------------------------------------------------------------------------
// rec0_seq: k-split, 512 threads = 8 waves = 2 waves/SIMD, waves_per_eu(2,2)
// pins the 256-VGPR budget so all 192 weight regs stay resident (round-2's
// VGPR_Count=128 showed the allocator was re-loading weights from L2 every
// step — the ~3200-cycle stall). out0h stores issue at the TOP of the next
// step from the freshly-read hvv registers (32 lanes, b128), so the store
// ack drains during the dot stream instead of serializing before the barrier.
// ---------------------------------------------------------------------------
__device__ void rec0_seq(char* smem, int rb,
                         const uint* __restrict__ Wk0n, const uint* __restrict__ wih0n,
                         const float* __restrict__ b_ih0, const float* __restrict__ b_hh0,
                         const float* __restrict__ x, f16* __restrict__ out0h,
                         float* __restrict__ hst, float* __restrict__ cst) {
    uint4* wlds4 = (uint4*)smem;                         // [4 q][4 mm][512] uint4 = 128 KB
    ushort* hs16 = (ushort*)(smem + 131072);             // [2 par][256] f16 = 1 KB
    float4* zb4  = (float4*)(smem + 132096);             // [256] float4 = 4 KB

    const int tid = threadIdx.x;
    const int dir = rb >> 6;
    const int b = rb & 63;
    const int u = tid & 255;
    const int kh = tid >> 8;
    const uint4* W4 = (const uint4*)Wk0n;

    #pragma unroll
    for (int q = 0; q < 4; ++q)
        #pragma unroll
        for (int mm = 0; mm < 4; ++mm)
            wlds4[(q * 4 + mm) * 512 + tid] =
                W4[((size_t)(dir * 4 + q) * 16 + 12 + mm) * 512 + tid];

    uint4 wr[4][12];
    #pragma unroll
    for (int q = 0; q < 4; ++q)
        #pragma unroll
        for (int m = 0; m < 12; ++m)
            wr[q][m] = W4[((size_t)(dir * 4 + q) * 16 + m) * 512 + tid];

    uint wih[12];
    float bias2[2];
    #pragma unroll
    for (int g2 = 0; g2 < 2; ++g2) {
        const int q = 2 * kh + g2;
        bias2[g2] = b_ih0[dir * NG + q * 256 + u] + b_hh0[dir * NG + q * 256 + u];
        #pragma unroll
        for (int dp = 0; dp < 6; ++dp)
            wih[g2 * 6 + dp] = wih0n[(dir * 12 + g2 * 6 + dp) * 512 + tid];
    }

    const int sidx = (dir * NB + b) * NH + u;
    const int seg = kh * 16 + (tid & 15);
    const bool storer = (tid & 255) < 16;
    float cv = 0.f, hv = 0.f;
    if (tid < 256) hs16[tid] = 0;
    __syncthreads();

    #pragma unroll 1
    for (int it = 0; it < NT; ++it) {
        const int par = it & 1;
        uint4 hvv = ((const uint4*)(hs16 + par * 256))[seg];

        // store h(it-1) for out0h from hvv (issued early; ack drains under dots)
        if (it > 0 && storer) {
            const int tprev = dir ? (NT - it) : (it - 1);
            *(uint4*)(out0h + ((size_t)b * NT + tprev) * 512 + dir * 256 + seg * 8) = hvv;
        }

        const int t = dir ? (NT - 1 - it) : it;
        const float4* xp = (const float4*)(x + ((size_t)b * NT + t) * DIN);
        float4 A = xp[0], B4 = xp[1], C4 = xp[2];
        uint xph[6] = {pkrtz(A.x, A.y), pkrtz(A.z, A.w), pkrtz(B4.x, B4.y),
                       pkrtz(B4.z, B4.w), pkrtz(C4.x, C4.y), pkrtz(C4.z, C4.w)};

        float ahA[4] = {0.f, 0.f, 0.f, 0.f};
        float ahB[4] = {0.f, 0.f, 0.f, 0.f};

        // ---- register groups g = 0..11 (kp kh*64 + 0..47) ----
        #pragma unroll
        for (int g = 0; g < 12; ++g) {
            RDL4(hvv, g, s0, s1, s2, s3);
            DOTS_GRP(ahA, ahB, wr[0][g], wr[1][g], wr[2][g], wr[3][g],
                     s0, s1, s2, s3);
        }
        // ---- LDS groups g = 12..15 (kp kh*64 + 48..63) ----
        #pragma unroll
        for (int gg = 0; gg < 4; ++gg) {
            uint4 l0 = wlds4[(0 * 4 + gg) * 512 + tid];
            uint4 l1 = wlds4[(1 * 4 + gg) * 512 + tid];
            uint4 l2 = wlds4[(2 * 4 + gg) * 512 + tid];
            uint4 l3 = wlds4[(3 * 4 + gg) * 512 + tid];
            RDL4(hvv, 12 + gg, s0, s1, s2, s3);
            DOTS_GRP(ahA, ahB, l0, l1, l2, l3, s0, s1, s2, s3);
        }

        // ---- input projection for this lane's 2 owned gates ----
        float xz0 = bias2[0], xz1 = bias2[1];
        #pragma unroll
        for (int d = 0; d < 6; ++d) {
            xz0 = dot2(wih[d], xph[d], xz0);
            xz1 = dot2(wih[6 + d], xph[d], xz1);
        }

        float p0 = ahA[0] + ahB[0], p1 = ahA[1] + ahB[1];
        float p2 = ahA[2] + ahB[2], p3 = ahA[3] + ahB[3];
        if (kh == 0) { p0 += xz0; p1 += xz1; }   // kh uniform per wave
        else         { p2 += xz0; p3 += xz1; }

        if (kh) zb4[u] = (float4){p0, p1, p2, p3};
        __syncthreads();                          // A: partials visible
        if (!kh) {
            float4 zp = zb4[u];
            float z0 = p0 + zp.x, z1 = p1 + zp.y;
            float z2 = p2 + zp.z, z3 = p3 + zp.w;
            cv = sigm(z1) * cv + sigm(z0) * tanh_(z2);
            hv = sigm(z3) * tanh_(cv);
            hs16[(par ^ 1) * 256 + u] = hbits((f16)hv);
        }
        __syncthreads();                          // B: new h visible
    }

    // epilogue: store h(NT-1) (sits in hs16[0] after the last iteration)
    if (storer) {
        uint4 hvf = ((const uint4*)(hs16 + 0 * 256))[seg];
        const int tlast = dir ? 0 : (NT - 1);
        *(uint4*)(out0h + ((size_t)b * NT + tlast) * 512 + dir * 256 + seg * 8) = hvf;
    }
    if (!kh) { cst[sidx] = cv; hst[sidx] = hv; }
}

// ---------------------------------------------------------------------------
// rec1_seq: k-split twin of rec0 (512 threads, pinned 2 waves/EU, resident
// weights). No per-step global store at all; xq (gate inputs from proj)
// loaded by kh=0 waves only, prefetched one step ahead.
// ---------------------------------------------------------------------------
__device__ void rec1_seq(char* smem, int rb, int chunk, int nsteps,
                         const uint* __restrict__ Wk1n, const float* __restrict__ xp1,
                         float* __restrict__ hst, float* __restrict__ cst,
                         float* __restrict__ hsm) {
    uint4* wlds4 = (uint4*)smem;                         // 128 KB
    ushort* hs16 = (ushort*)(smem + 131072);             // 1 KB
    float4* zb4  = (float4*)(smem + 132096);             // 4 KB

    const int tid = threadIdx.x;
    const int dir = rb >> 6;
    const int b = rb & 63;
    const int u = tid & 255;
    const int kh = tid >> 8;
    const int ld = 2 + dir;
    const uint4* W4 = (const uint4*)Wk1n;

    #pragma unroll
    for (int q = 0; q < 4; ++q)
        #pragma unroll
        for (int mm = 0; mm < 4; ++mm)
            wlds4[(q * 4 + mm) * 512 + tid] =
                W4[((size_t)(dir * 4 + q) * 16 + 12 + mm) * 512 + tid];

    uint4 wr[4][12];
    #pragma unroll
    for (int q = 0; q < 4; ++q)
        #pragma unroll
        for (int m = 0; m < 12; ++m)
            wr[q][m] = W4[((size_t)(dir * 4 + q) * 16 + m) * 512 + tid];

    const int sidx = (ld * NB + b) * NH + u;
    const int seg = kh * 16 + (tid & 15);
    float cv = 0.f, hv = 0.f, hsv = 0.f;
    if (chunk > 0 && !kh) {
        cv = cst[sidx]; hv = hst[sidx];
        hsv = hsm[(dir * NB + b) * NH + u];
    }
    if (tid < 256) hs16[tid] = hbits((f16)hv);

    const float* xbase = xp1 + ((size_t)dir * NB + b) * TCL * NG + u * 4;
    float4 xq_cur = {0.f, 0.f, 0.f, 0.f};
    if (!kh) xq_cur = *(const float4*)xbase;
    __syncthreads();

    #pragma unroll 1
    for (int it = 0; it < nsteps; ++it) {
        const int par = it & 1;
        uint4 hvv = ((const uint4*)(hs16 + par * 256))[seg];

        float4 xq_nxt = xq_cur;
        if (!kh) {
            const int itn = (it + 1 < nsteps) ? (it + 1) : it;
            xq_nxt = *(const float4*)(xbase + (size_t)itn * NG);
        }

        float ahA[4] = {0.f, 0.f, 0.f, 0.f};
        float ahB[4] = {0.f, 0.f, 0.f, 0.f};

        #pragma unroll
        for (int g = 0; g < 12; ++g) {
            RDL4(hvv, g, s0, s1, s2, s3);
            DOTS_GRP(ahA, ahB, wr[0][g], wr[1][g], wr[2][g], wr[3][g],
                     s0, s1, s2, s3);
        }
        #pragma unroll
        for (int gg = 0; gg < 4; ++gg) {
            uint4 l0 = wlds4[(0 * 4 + gg) * 512 + tid];
            uint4 l1 = wlds4[(1 * 4 + gg) * 512 + tid];
            uint4 l2 = wlds4[(2 * 4 + gg) * 512 + tid];
            uint4 l3 = wlds4[(3 * 4 + gg) * 512 + tid];
            RDL4(hvv, 12 + gg, s0, s1, s2, s3);
            DOTS_GRP(ahA, ahB, l0, l1, l2, l3, s0, s1, s2, s3);
        }

        float p0 = ahA[0] + ahB[0], p1 = ahA[1] + ahB[1];
        float p2 = ahA[2] + ahB[2], p3 = ahA[3] + ahB[3];

        if (kh) zb4[u] = (float4){p0, p1, p2, p3};
        __syncthreads();                          // A: partials visible
        if (!kh) {
            float4 zp = zb4[u];
            float z0 = p0 + zp.x + xq_cur.x;
            float z1 = p1 + zp.y + xq_cur.y;
            float z2 = p2 + zp.z + xq_cur.z;
            float z3 = p3 + zp.w + xq_cur.w;
            cv = sigm(z1) * cv + sigm(z0) * tanh_(z2);
            hv = sigm(z3) * tanh_(cv);
            hsv += hv;
            hs16[(par ^ 1) * 256 + u] = hbits((f16)hv);
        }
        __syncthreads();                          // B: new h visible
        xq_cur = xq_nxt;
    }

    if (!kh) {
        cst[sidx] = cv; hst[sidx] = hv;
        hsm[(dir * NB + b) * NH + u] = hsv;
    }
}

// ---------------------------------------------------------------------------
// proj_role (chunk c): fp16 MFMA 16x16x32 direct-from-global. Now 512-thread
// blocks: 8 waves, each wave handles 1 m-tile (was 4 waves x 2).
// ---------------------------------------------------------------------------
__device__ void proj_role(int pb, int c,
                          const f16* __restrict__ out0h, const f16* __restrict__ wih1h,
                          const float* __restrict__ bsum1, float* __restrict__ xp1) {
    const int tid = threadIdx.x;
    const int w = tid >> 6, l = tid & 63;
    const int lane16 = l & 15, quad = l >> 4;

    const int mtg = pb * 8 + w;                // 0..1023
    const int dirt = mtg >> 9;
    const int mtl = mtg & 511;

    const int ra = mtl * 16 + lane16;          // row over b(64) x tl(128)
    const int ab = ra >> 7, tla = ra & 127;
    const int ta = dirt ? (NT - 1 - c * TCL - tla) : (c * TCL + tla);
    const f16* Arow = out0h + ((size_t)ab * NT + ta) * 512 + quad * 8;

    uint4 afr[16];
    #pragma unroll
    for (int kt = 0; kt < 16; ++kt) afr[kt] = *(const uint4*)(Arow + kt * 32);

    int ob[4], otl[4];
    #pragma unroll
    for (int reg = 0; reg < 4; ++reg) {
        int rr = mtl * 16 + quad * 4 + reg;
        ob[reg] = rr >> 7; otl[reg] = rr & 127;
    }

    const f16* Bbase = wih1h + (size_t)dirt * NG * 512 + quad * 8;

    #pragma unroll 1
    for (int nt = 0; nt < 64; ++nt) {
        const int col = nt * 16 + lane16;
        const f16* Brow = Bbase + (size_t)col * 512;
        float bias = bsum1[dirt * NG + col];

        f32x4 acc = {0.f, 0.f, 0.f, 0.f};
        #pragma unroll
        for (int kt = 0; kt < 16; ++kt) {
            uint4 bv = *(const uint4*)(Brow + kt * 32);
            acc = __builtin_amdgcn_mfma_f32_16x16x32_f16(
                __builtin_bit_cast(f16x8, afr[kt]),
                __builtin_bit_cast(f16x8, bv), acc, 0, 0, 0);
        }
        const int ucol = col & 255, qcol = col >> 8;
        #pragma unroll
        for (int reg = 0; reg < 4; ++reg) {
            xp1[((size_t)(dirt * NB + ob[reg]) * TCL + otl[reg]) * NG
                + ucol * 4 + qcol] = acc[reg] + bias;
        }
    }
}

// ---------------------------------------------------------------------------
// Phase A: layer 0. 128 blocks x 512 threads; EXACTLY 2 waves/EU so the
// allocator gets the 256-VGPR budget and keeps the 192 weight regs resident.
// ---------------------------------------------------------------------------
__global__ __launch_bounds__(512)
__attribute__((amdgpu_waves_per_eu(2, 2)))
void k_rec0(
    const uint* __restrict__ Wk0n, const uint* __restrict__ wih0n,
    const float* __restrict__ b_ih0, const float* __restrict__ b_hh0,
    const float* __restrict__ x, f16* __restrict__ out0h,
    float* __restrict__ hst, float* __restrict__ cst) {
    extern __shared__ __align__(16) char smem[];
    rec0_seq(smem, blockIdx.x, Wk0n, wih0n, b_ih0, b_hh0, x, out0h, hst, cst);
}

// ---------------------------------------------------------------------------
// Phase B launch j: blocks 0..127 = rec1 chunk j-1; blocks 128..255 = proj
// chunk j. 512 threads now (rec1 k-split); proj uses 8 waves x 1 m-tile.
// ---------------------------------------------------------------------------
__global__ __launch_bounds__(512)
__attribute__((amdgpu_waves_per_eu(2, 2)))
void k_pipe(
    int j,
    const uint* __restrict__ Wk1n,
    const f16* __restrict__ out0h, const f16* __restrict__ wih1h,
    const float* __restrict__ bsum1, float* __restrict__ xp1,
    float* __restrict__ hst, float* __restrict__ cst, float* __restrict__ hsm) {
    extern __shared__ __align__(16) char smem[];
    const int bid = blockIdx.x;
    if (bid < 128) {
        const int cc = j - 1;
        if (cc >= 0 && cc < NCHUNK)
            rec1_seq(smem, bid, cc, TCL, Wk1n,
                     xp1 + (size_t)(cc & 1) * XPS, hst, cst, hsm);
    } else {
        const int cp = j;
        if (cp < NCHUNK)
            proj_role(bid - 128, cp, out0h, wih1h, bsum1,
                      xp1 + (size_t)(cp & 1) * XPS);
    }
}

// ---------------------------------------------------------------------------
__global__ void k_fc(const float* __restrict__ hsm, const float* __restrict__ fc_w,
                     const float* __restrict__ fc_b, float* __restrict__ out) {
    const int b = blockIdx.x;
    const int n = threadIdx.x;
    if (n >= NCLS) return;
    float acc = fc_b[n];
    const float inv = 1.0f / (float)NT;
    for (int k = 0; k < 2 * NH; ++k) {
        float pv = hsm[((k >> 8) * NB + b) * NH + (k & 255)];
        acc += (pv * inv) * fc_w[n * 2 * NH + k];
    }
    out[b * NCLS + n] = acc;
}

// ---------------------------------------------------------------------------
extern "C" void kernel_launch(void* const* d_in, const int* in_sizes, int n_in,
                              void* d_out, int out_size, void* d_ws, size_t ws_size,
                              hipStream_t stream) {
    const float* x     = (const float*)d_in[0];
    const float* w_ih0 = (const float*)d_in[1];
    const float* w_hh0 = (const float*)d_in[2];
    const float* b_ih0 = (const float*)d_in[3];
    const float* b_hh0 = (const float*)d_in[4];
    const float* w_ih1 = (const float*)d_in[5];
    const float* w_hh1 = (const float*)d_in[6];
    const float* b_ih1 = (const float*)d_in[7];
    const float* b_hh1 = (const float*)d_in[8];
    const float* fc_w  = (const float*)d_in[9];
    const float* fc_b  = (const float*)d_in[10];
    float* out = (float*)d_out;

    char* ws = (char*)d_ws;
    uint* Wk0n  = (uint*)ws;                      // 262144 u
    uint* wih0n = Wk0n + 262144;                  // 12288 u
    uint* Wk1n  = wih0n + 12288;                  // 262144 u
    f16* wih1h  = (f16*)(Wk1n + 262144);          // 1048576 h = 2 MB
    float* bsum1 = (float*)(wih1h + 1048576);     // 2048 f
    float* hst  = bsum1 + 2048;                   // 65536 f
    float* cst  = hst + 65536;                    // 65536 f
    float* hsm  = cst + 65536;                    // 32768 f
    float* xp1  = hsm + 32768;                    // 2 x 16777216 f = 128 MB
    f16* out0h  = (f16*)(xp1 + 2 * XPS);          // 33554432 h = 64 MB

    k_prep<<<dim3(4096), dim3(256), 0, stream>>>(
        w_hh0, w_hh1, w_ih0, w_ih1, b_ih1, b_hh1,
        Wk0n, wih0n, Wk1n, wih1h, bsum1);

    k_rec0<<<dim3(128), dim3(512), 136192, stream>>>(
        Wk0n, wih0n, b_ih0, b_hh0, x, out0h, hst, cst);

    for (int j = 0; j <= NCHUNK; ++j) {
        k_pipe<<<dim3(256), dim3(512), 136192, stream>>>(
            j, Wk1n, out0h, wih1h, bsum1, xp1, hst, cst, hsm);
    }

    k_fc<<<dim3(64), dim3(32), 0, stream>>>(hsm, fc_w, fc_b, out);
}

// Round 4
// 4270.817 us; speedup vs baseline: 1.0944x; 1.0037x over previous
//
#include <hip/hip_runtime.h>

#define NB 64
#define NT 1024
#define DIN 12
#define NH 256
#define NG 1024
#define NCLS 17
#define TCL 128
#define NCHUNK 8
#define XPS ((size_t)2 * NB * TCL * NG)   // floats per xp1 chunk buffer

typedef _Float16 f16;
typedef __attribute__((ext_vector_type(2))) _Float16 half2_t;
typedef __attribute__((ext_vector_type(8))) _Float16 f16x8;
typedef __attribute__((ext_vector_type(4))) float f32x4;
typedef unsigned int uint;
typedef unsigned short ushort;

struct U4 { uint x, y, z, w; };   // plain struct so components pin cleanly

__device__ __forceinline__ float sigm(float v) { return 1.0f / (1.0f + __expf(-v)); }
__device__ __forceinline__ float tanh_(float v) {
    v = fminf(fmaxf(v, -15.0f), 15.0f);
    float e = __expf(2.0f * v);
    return (e - 1.0f) / (e + 1.0f);
}
__device__ __forceinline__ float dot2(uint w, uint h, float c) {
    return __builtin_amdgcn_fdot2(__builtin_bit_cast(half2_t, w),
                                  __builtin_bit_cast(half2_t, h), c, false);
}
__device__ __forceinline__ uint pack16(float a, float b) {
    union { f16 h[2]; uint u; } cv; cv.h[0] = (f16)a; cv.h[1] = (f16)b; return cv.u;
}
__device__ __forceinline__ uint pkrtz(float a, float b) {
    return __builtin_bit_cast(uint, __builtin_amdgcn_cvt_pkrtz(a, b));
}
__device__ __forceinline__ ushort hbits(f16 v) {
    union { f16 h; ushort u; } cv; cv.h = v; return cv.u;
}
__device__ __forceinline__ uint rdlane(uint v, int l) {
    return (uint)__builtin_amdgcn_readlane((int)v, l);
}

// ---------------------------------------------------------------------------
// Comp-major interleave over 8 accumulators.
// ---------------------------------------------------------------------------
#define RDL4(HV, G, S0, S1, S2, S3)                                           \
    uint S0 = rdlane((HV).x, (G)), S1 = rdlane((HV).y, (G)),                  \
         S2 = rdlane((HV).z, (G)), S3 = rdlane((HV).w, (G))

#define DOTS_GRP(AH, BH, W0, W1, W2, W3, S0, S1, S2, S3) do {                 \
    AH[0] = dot2((W0).x, (S0), AH[0]); AH[1] = dot2((W1).x, (S0), AH[1]);     \
    AH[2] = dot2((W2).x, (S0), AH[2]); AH[3] = dot2((W3).x, (S0), AH[3]);     \
    BH[0] = dot2((W0).y, (S1), BH[0]); BH[1] = dot2((W1).y, (S1), BH[1]);     \
    BH[2] = dot2((W2).y, (S1), BH[2]); BH[3] = dot2((W3).y, (S1), BH[3]);     \
    AH[0] = dot2((W0).z, (S2), AH[0]); AH[1] = dot2((W1).z, (S2), AH[1]);     \
    AH[2] = dot2((W2).z, (S2), AH[2]); AH[3] = dot2((W3).z, (S2), AH[3]);     \
    BH[0] = dot2((W0).w, (S3), BH[0]); BH[1] = dot2((W1).w, (S3), BH[1]);     \
    BH[2] = dot2((W2).w, (S3), BH[2]); BH[3] = dot2((W3).w, (S3), BH[3]);     \
} while (0)

// Pin a U4's components: opaque to the optimizer, so the values CANNOT be
// rematerialized by re-loading from global inside the step loop. This is
// what actually forces weight residency (waves_per_eu alone did not — the
// pre-RA scheduler sank the loads and RA settled at 128 VGPRs).
#define PIN4(W) asm volatile("" : "+v"((W).x), "+v"((W).y), "+v"((W).z), "+v"((W).w))

// ---------------------------------------------------------------------------
// k_prep: unified k-split packing for BOTH recurrence layers.
// Wk{0,1}n [dir][q][m 0..15][t512] uint4: uint4 #m of lane t512=(u,kh) holds
// w_hh[dir][q*256+u][2*kp..2*kp+1] for kp = kh*64+4m+c, c=0..3.
// ---------------------------------------------------------------------------
__global__ void k_prep(const float* __restrict__ w_hh0, const float* __restrict__ w_hh1,
                       const float* __restrict__ w_ih0, const float* __restrict__ w_ih1,
                       const float* __restrict__ b_ih1, const float* __restrict__ b_hh1,
                       uint* __restrict__ Wk0n, uint* __restrict__ wih0n,
                       uint* __restrict__ Wk1n,
                       f16* __restrict__ wih1h, float* __restrict__ bsum1) {
    int i = blockIdx.x * 256 + threadIdx.x;
    if (i < 262144) {                      // Wk0n
        int c = i & 3; int r = i >> 2;
        int t512 = r & 511; int s = r >> 9;
        int m = s & 15, q = (s >> 4) & 3, dir = s >> 6;
        int u = t512 & 255, kh = t512 >> 8;
        int kp = kh * 64 + 4 * m + c;
        const float* row = w_hh0 + (size_t)dir * NG * NH + (size_t)(q * 256 + u) * NH;
        Wk0n[i] = pack16(row[2 * kp], row[2 * kp + 1]);
    }
    if (i < 262144) {                      // Wk1n (same layout, layer 1)
        int c = i & 3; int r = i >> 2;
        int t512 = r & 511; int s = r >> 9;
        int m = s & 15, q = (s >> 4) & 3, dir = s >> 6;
        int u = t512 & 255, kh = t512 >> 8;
        int kp = kh * 64 + 4 * m + c;
        const float* row = w_hh1 + (size_t)dir * NG * NH + (size_t)(q * 256 + u) * NH;
        Wk1n[i] = pack16(row[2 * kp], row[2 * kp + 1]);
    }
    if (i < 12288) {                       // wih0n: [dir][g2*6+dp][t512]
        int t512 = i & 511; int r = i >> 9;
        int dp = r % 6, g2 = (r / 6) & 1, dir = r / 12;
        int q = 2 * (t512 >> 8) + g2, u = t512 & 255;
        const float* row = w_ih0 + ((size_t)dir * NG + q * 256 + u) * DIN;
        wih0n[i] = pack16(row[2 * dp], row[2 * dp + 1]);
    }
    if (i < 2 * NG * 2 * NH) wih1h[i] = (f16)w_ih1[i];
    if (i < 2 * NG) bsum1[i] = b_ih1[i] + b_hh1[i];
}

// ---------------------------------------------------------------------------
// rec0_seq: k-split, 512 threads = 2 waves/SIMD. Weight registers PINNED
// (PIN4) so they stay VGPR-resident: round-3 counters proved the compiler
// was re-loading ~48 b128/lane/step from L2 (393 KB/CU/step ≈ the whole
// step time at L2 BW) with VGPR_Count=128. x prefetched one step ahead.
// ---------------------------------------------------------------------------
__device__ void rec0_seq(char* smem, int rb,
                         const uint* __restrict__ Wk0n, const uint* __restrict__ wih0n,
                         const float* __restrict__ b_ih0, const float* __restrict__ b_hh0,
                         const float* __restrict__ x, f16* __restrict__ out0h,
                         float* __restrict__ hst, float* __restrict__ cst) {
    uint4* wlds4 = (uint4*)smem;                         // [4 q][4 mm][512] uint4 = 128 KB
    ushort* hs16 = (ushort*)(smem + 131072);             // [2 par][256] f16 = 1 KB
    float4* zb4  = (float4*)(smem + 132096);             // [256] float4 = 4 KB

    const int tid = threadIdx.x;
    const int dir = rb >> 6;
    const int b = rb & 63;
    const int u = tid & 255;
    const int kh = tid >> 8;
    const uint4* W4 = (const uint4*)Wk0n;

    #pragma unroll
    for (int q = 0; q < 4; ++q)
        #pragma unroll
        for (int mm = 0; mm < 4; ++mm)
            wlds4[(q * 4 + mm) * 512 + tid] =
                W4[((size_t)(dir * 4 + q) * 16 + 12 + mm) * 512 + tid];

    U4 wr[4][12];
    #pragma unroll
    for (int q = 0; q < 4; ++q)
        #pragma unroll
        for (int m = 0; m < 12; ++m) {
            uint4 t = W4[((size_t)(dir * 4 + q) * 16 + m) * 512 + tid];
            wr[q][m].x = t.x; wr[q][m].y = t.y; wr[q][m].z = t.z; wr[q][m].w = t.w;
        }
    #pragma unroll
    for (int q = 0; q < 4; ++q)
        #pragma unroll
        for (int m = 0; m < 12; ++m) PIN4(wr[q][m]);

    uint wih[12];
    float bias2[2];
    #pragma unroll
    for (int g2 = 0; g2 < 2; ++g2) {
        const int q = 2 * kh + g2;
        bias2[g2] = b_ih0[dir * NG + q * 256 + u] + b_hh0[dir * NG + q * 256 + u];
        #pragma unroll
        for (int dp = 0; dp < 6; ++dp)
            wih[g2 * 6 + dp] = wih0n[(dir * 12 + g2 * 6 + dp) * 512 + tid];
    }
    #pragma unroll
    for (int d = 0; d < 12; d += 4)
        asm volatile("" : "+v"(wih[d]), "+v"(wih[d+1]), "+v"(wih[d+2]), "+v"(wih[d+3]));

    const int sidx = (dir * NB + b) * NH + u;
    const int seg = kh * 16 + (tid & 15);
    const bool storer = (tid & 255) < 16;
    float cv = 0.f, hv = 0.f;
    if (tid < 256) hs16[tid] = 0;

    const float4* xb = (const float4*)(x + ((size_t)b * NT + (dir ? NT - 1 : 0)) * DIN);
    const long xstep = dir ? -3 : 3;            // float4 stride per timestep
    float4 xA = xb[0], xB = xb[1], xC = xb[2];  // x for step 0
    __syncthreads();

    #pragma unroll 1
    for (int it = 0; it < NT; ++it) {
        const int par = it & 1;
        uint4 hvv = ((const uint4*)(hs16 + par * 256))[seg];

        // store h(it-1) for out0h from hvv (ack drains under the dot stream)
        if (it > 0 && storer) {
            const int tprev = dir ? (NT - it) : (it - 1);
            *(uint4*)(out0h + ((size_t)b * NT + tprev) * 512 + dir * 256 + seg * 8) = hvv;
        }

        // prefetch next step's x
        const long xo = (it + 1 < NT) ? (long)(it + 1) * xstep : (long)it * xstep;
        float4 xAn = xb[xo], xBn = xb[xo + 1], xCn = xb[xo + 2];

        uint xph[6] = {pkrtz(xA.x, xA.y), pkrtz(xA.z, xA.w), pkrtz(xB.x, xB.y),
                       pkrtz(xB.z, xB.w), pkrtz(xC.x, xC.y), pkrtz(xC.z, xC.w)};

        float ahA[4] = {0.f, 0.f, 0.f, 0.f};
        float ahB[4] = {0.f, 0.f, 0.f, 0.f};

        // ---- register groups g = 0..11 (kp kh*64 + 0..47) ----
        #pragma unroll
        for (int g = 0; g < 12; ++g) {
            RDL4(hvv, g, s0, s1, s2, s3);
            DOTS_GRP(ahA, ahB, wr[0][g], wr[1][g], wr[2][g], wr[3][g],
                     s0, s1, s2, s3);
        }
        // ---- LDS groups g = 12..15 (kp kh*64 + 48..63) ----
        #pragma unroll
        for (int gg = 0; gg < 4; ++gg) {
            uint4 l0 = wlds4[(0 * 4 + gg) * 512 + tid];
            uint4 l1 = wlds4[(1 * 4 + gg) * 512 + tid];
            uint4 l2 = wlds4[(2 * 4 + gg) * 512 + tid];
            uint4 l3 = wlds4[(3 * 4 + gg) * 512 + tid];
            RDL4(hvv, 12 + gg, s0, s1, s2, s3);
            DOTS_GRP(ahA, ahB, l0, l1, l2, l3, s0, s1, s2, s3);
        }

        // ---- input projection for this lane's 2 owned gates ----
        float xz0 = bias2[0], xz1 = bias2[1];
        #pragma unroll
        for (int d = 0; d < 6; ++d) {
            xz0 = dot2(wih[d], xph[d], xz0);
            xz1 = dot2(wih[6 + d], xph[d], xz1);
        }

        float p0 = ahA[0] + ahB[0], p1 = ahA[1] + ahB[1];
        float p2 = ahA[2] + ahB[2], p3 = ahA[3] + ahB[3];
        if (kh == 0) { p0 += xz0; p1 += xz1; }   // kh uniform per wave
        else         { p2 += xz0; p3 += xz1; }

        if (kh) zb4[u] = (float4){p0, p1, p2, p3};
        __syncthreads();                          // A: partials visible
        if (!kh) {
            float4 zp = zb4[u];
            float z0 = p0 + zp.x, z1 = p1 + zp.y;
            float z2 = p2 + zp.z, z3 = p3 + zp.w;
            cv = sigm(z1) * cv + sigm(z0) * tanh_(z2);
            hv = sigm(z3) * tanh_(cv);
            hs16[(par ^ 1) * 256 + u] = hbits((f16)hv);
        }
        __syncthreads();                          // B: new h visible
        xA = xAn; xB = xBn; xC = xCn;
    }

    // epilogue: store h(NT-1) (sits in hs16[0] after the last iteration)
    if (storer) {
        uint4 hvf = ((const uint4*)(hs16 + 0 * 256))[seg];
        const int tlast = dir ? 0 : (NT - 1);
        *(uint4*)(out0h + ((size_t)b * NT + tlast) * 512 + dir * 256 + seg * 8) = hvf;
    }
    if (!kh) { cst[sidx] = cv; hst[sidx] = hv; }
}

// ---------------------------------------------------------------------------
// rec1_seq: k-split twin of rec0, weights pinned the same way.
// ---------------------------------------------------------------------------
__device__ void rec1_seq(char* smem, int rb, int chunk, int nsteps,
                         const uint* __restrict__ Wk1n, const float* __restrict__ xp1,
                         float* __restrict__ hst, float* __restrict__ cst,
                         float* __restrict__ hsm) {
    uint4* wlds4 = (uint4*)smem;                         // 128 KB
    ushort* hs16 = (ushort*)(smem + 131072);             // 1 KB
    float4* zb4  = (float4*)(smem + 132096);             // 4 KB

    const int tid = threadIdx.x;
    const int dir = rb >> 6;
    const int b = rb & 63;
    const int u = tid & 255;
    const int kh = tid >> 8;
    const int ld = 2 + dir;
    const uint4* W4 = (const uint4*)Wk1n;

    #pragma unroll
    for (int q = 0; q < 4; ++q)
        #pragma unroll
        for (int mm = 0; mm < 4; ++mm)
            wlds4[(q * 4 + mm) * 512 + tid] =
                W4[((size_t)(dir * 4 + q) * 16 + 12 + mm) * 512 + tid];

    U4 wr[4][12];
    #pragma unroll
    for (int q = 0; q < 4; ++q)
        #pragma unroll
        for (int m = 0; m < 12; ++m) {
            uint4 t = W4[((size_t)(dir * 4 + q) * 16 + m) * 512 + tid];
            wr[q][m].x = t.x; wr[q][m].y = t.y; wr[q][m].z = t.z; wr[q][m].w = t.w;
        }
    #pragma unroll
    for (int q = 0; q < 4; ++q)
        #pragma unroll
        for (int m = 0; m < 12; ++m) PIN4(wr[q][m]);

    const int sidx = (ld * NB + b) * NH + u;
    const int seg = kh * 16 + (tid & 15);
    float cv = 0.f, hv = 0.f, hsv = 0.f;
    if (chunk > 0 && !kh) {
        cv = cst[sidx]; hv = hst[sidx];
        hsv = hsm[(dir * NB + b) * NH + u];
    }
    if (tid < 256) hs16[tid] = hbits((f16)hv);

    const float* xbase = xp1 + ((size_t)dir * NB + b) * TCL * NG + u * 4;
    float4 xq_cur = {0.f, 0.f, 0.f, 0.f};
    if (!kh) xq_cur = *(const float4*)xbase;
    __syncthreads();

    #pragma unroll 1
    for (int it = 0; it < nsteps; ++it) {
        const int par = it & 1;
        uint4 hvv = ((const uint4*)(hs16 + par * 256))[seg];

        float4 xq_nxt = xq_cur;
        if (!kh) {
            const int itn = (it + 1 < nsteps) ? (it + 1) : it;
            xq_nxt = *(const float4*)(xbase + (size_t)itn * NG);
        }

        float ahA[4] = {0.f, 0.f, 0.f, 0.f};
        float ahB[4] = {0.f, 0.f, 0.f, 0.f};

        #pragma unroll
        for (int g = 0; g < 12; ++g) {
            RDL4(hvv, g, s0, s1, s2, s3);
            DOTS_GRP(ahA, ahB, wr[0][g], wr[1][g], wr[2][g], wr[3][g],
                     s0, s1, s2, s3);
        }
        #pragma unroll
        for (int gg = 0; gg < 4; ++gg) {
            uint4 l0 = wlds4[(0 * 4 + gg) * 512 + tid];
            uint4 l1 = wlds4[(1 * 4 + gg) * 512 + tid];
            uint4 l2 = wlds4[(2 * 4 + gg) * 512 + tid];
            uint4 l3 = wlds4[(3 * 4 + gg) * 512 + tid];
            RDL4(hvv, 12 + gg, s0, s1, s2, s3);
            DOTS_GRP(ahA, ahB, l0, l1, l2, l3, s0, s1, s2, s3);
        }

        float p0 = ahA[0] + ahB[0], p1 = ahA[1] + ahB[1];
        float p2 = ahA[2] + ahB[2], p3 = ahA[3] + ahB[3];

        if (kh) zb4[u] = (float4){p0, p1, p2, p3};
        __syncthreads();                          // A: partials visible
        if (!kh) {
            float4 zp = zb4[u];
            float z0 = p0 + zp.x + xq_cur.x;
            float z1 = p1 + zp.y + xq_cur.y;
            float z2 = p2 + zp.z + xq_cur.z;
            float z3 = p3 + zp.w + xq_cur.w;
            cv = sigm(z1) * cv + sigm(z0) * tanh_(z2);
            hv = sigm(z3) * tanh_(cv);
            hsv += hv;
            hs16[(par ^ 1) * 256 + u] = hbits((f16)hv);
        }
        __syncthreads();                          // B: new h visible
        xq_cur = xq_nxt;
    }

    if (!kh) {
        cst[sidx] = cv; hst[sidx] = hv;
        hsm[(dir * NB + b) * NH + u] = hsv;
    }
}

// ---------------------------------------------------------------------------
// proj_role (chunk c): fp16 MFMA 16x16x32 direct-from-global. 512-thread
// blocks: 8 waves, each wave handles 1 m-tile.
// ---------------------------------------------------------------------------
__device__ void proj_role(int pb, int c,
                          const f16* __restrict__ out0h, const f16* __restrict__ wih1h,
                          const float* __restrict__ bsum1, float* __restrict__ xp1) {
    const int tid = threadIdx.x;
    const int w = tid >> 6, l = tid & 63;
    const int lane16 = l & 15, quad = l >> 4;

    const int mtg = pb * 8 + w;                // 0..1023
    const int dirt = mtg >> 9;
    const int mtl = mtg & 511;

    const int ra = mtl * 16 + lane16;          // row over b(64) x tl(128)
    const int ab = ra >> 7, tla = ra & 127;
    const int ta = dirt ? (NT - 1 - c * TCL - tla) : (c * TCL + tla);
    const f16* Arow = out0h + ((size_t)ab * NT + ta) * 512 + quad * 8;

    uint4 afr[16];
    #pragma unroll
    for (int kt = 0; kt < 16; ++kt) afr[kt] = *(const uint4*)(Arow + kt * 32);

    int ob[4], otl[4];
    #pragma unroll
    for (int reg = 0; reg < 4; ++reg) {
        int rr = mtl * 16 + quad * 4 + reg;
        ob[reg] = rr >> 7; otl[reg] = rr & 127;
    }

    const f16* Bbase = wih1h + (size_t)dirt * NG * 512 + quad * 8;

    #pragma unroll 1
    for (int nt = 0; nt < 64; ++nt) {
        const int col = nt * 16 + lane16;
        const f16* Brow = Bbase + (size_t)col * 512;
        float bias = bsum1[dirt * NG + col];

        f32x4 acc = {0.f, 0.f, 0.f, 0.f};
        #pragma unroll
        for (int kt = 0; kt < 16; ++kt) {
            uint4 bv = *(const uint4*)(Brow + kt * 32);
            acc = __builtin_amdgcn_mfma_f32_16x16x32_f16(
                __builtin_bit_cast(f16x8, afr[kt]),
                __builtin_bit_cast(f16x8, bv), acc, 0, 0, 0);
        }
        const int ucol = col & 255, qcol = col >> 8;
        #pragma unroll
        for (int reg = 0; reg < 4; ++reg) {
            xp1[((size_t)(dirt * NB + ob[reg]) * TCL + otl[reg]) * NG
                + ucol * 4 + qcol] = acc[reg] + bias;
        }
    }
}

// ---------------------------------------------------------------------------
// Phase A: layer 0. 128 blocks x 512 threads, pinned weights, 2 waves/EU.
// ---------------------------------------------------------------------------
__global__ __launch_bounds__(512)
__attribute__((amdgpu_waves_per_eu(2, 2)))
void k_rec0(
    const uint* __restrict__ Wk0n, const uint* __restrict__ wih0n,
    const float* __restrict__ b_ih0, const float* __restrict__ b_hh0,
    const float* __restrict__ x, f16* __restrict__ out0h,
    float* __restrict__ hst, float* __restrict__ cst) {
    extern __shared__ __align__(16) char smem[];
    rec0_seq(smem, blockIdx.x, Wk0n, wih0n, b_ih0, b_hh0, x, out0h, hst, cst);
}

// ---------------------------------------------------------------------------
// Phase B launch j: blocks 0..127 = rec1 chunk j-1; blocks 128..255 = proj
// chunk j.
// ---------------------------------------------------------------------------
__global__ __launch_bounds__(512)
__attribute__((amdgpu_waves_per_eu(2, 2)))
void k_pipe(
    int j,
    const uint* __restrict__ Wk1n,
    const f16* __restrict__ out0h, const f16* __restrict__ wih1h,
    const float* __restrict__ bsum1, float* __restrict__ xp1,
    float* __restrict__ hst, float* __restrict__ cst, float* __restrict__ hsm) {
    extern __shared__ __align__(16) char smem[];
    const int bid = blockIdx.x;
    if (bid < 128) {
        const int cc = j - 1;
        if (cc >= 0 && cc < NCHUNK)
            rec1_seq(smem, bid, cc, TCL, Wk1n,
                     xp1 + (size_t)(cc & 1) * XPS, hst, cst, hsm);
    } else {
        const int cp = j;
        if (cp < NCHUNK)
            proj_role(bid - 128, cp, out0h, wih1h, bsum1,
                      xp1 + (size_t)(cp & 1) * XPS);
    }
}

// ---------------------------------------------------------------------------
__global__ void k_fc(const float* __restrict__ hsm, const float* __restrict__ fc_w,
                     const float* __restrict__ fc_b, float* __restrict__ out) {
    const int b = blockIdx.x;
    const int n = threadIdx.x;
    if (n >= NCLS) return;
    float acc = fc_b[n];
    const float inv = 1.0f / (float)NT;
    for (int k = 0; k < 2 * NH; ++k) {
        float pv = hsm[((k >> 8) * NB + b) * NH + (k & 255)];
        acc += (pv * inv) * fc_w[n * 2 * NH + k];
    }
    out[b * NCLS + n] = acc;
}

// ---------------------------------------------------------------------------
extern "C" void kernel_launch(void* const* d_in, const int* in_sizes, int n_in,
                              void* d_out, int out_size, void* d_ws, size_t ws_size,
                              hipStream_t stream) {
    const float* x     = (const float*)d_in[0];
    const float* w_ih0 = (const float*)d_in[1];
    const float* w_hh0 = (const float*)d_in[2];
    const float* b_ih0 = (const float*)d_in[3];
    const float* b_hh0 = (const float*)d_in[4];
    const float* w_ih1 = (const float*)d_in[5];
    const float* w_hh1 = (const float*)d_in[6];
    const float* b_ih1 = (const float*)d_in[7];
    const float* b_hh1 = (const float*)d_in[8];
    const float* fc_w  = (const float*)d_in[9];
    const float* fc_b  = (const float*)d_in[10];
    float* out = (float*)d_out;

    char* ws = (char*)d_ws;
    uint* Wk0n  = (uint*)ws;                      // 262144 u
    uint* wih0n = Wk0n + 262144;                  // 12288 u
    uint* Wk1n  = wih0n + 12288;                  // 262144 u
    f16* wih1h  = (f16*)(Wk1n + 262144);          // 1048576 h = 2 MB
    float* bsum1 = (float*)(wih1h + 1048576);     // 2048 f
    float* hst  = bsum1 + 2048;                   // 65536 f
    float* cst  = hst + 65536;                    // 65536 f
    float* hsm  = cst + 65536;                    // 32768 f
    float* xp1  = hsm + 32768;                    // 2 x 16777216 f = 128 MB
    f16* out0h  = (f16*)(xp1 + 2 * XPS);          // 33554432 h = 64 MB

    k_prep<<<dim3(4096), dim3(256), 0, stream>>>(
        w_hh0, w_hh1, w_ih0, w_ih1, b_ih1, b_hh1,
        Wk0n, wih0n, Wk1n, wih1h, bsum1);

    k_rec0<<<dim3(128), dim3(512), 136192, stream>>>(
        Wk0n, wih0n, b_ih0, b_hh0, x, out0h, hst, cst);

    for (int j = 0; j <= NCHUNK; ++j) {
        k_pipe<<<dim3(256), dim3(512), 136192, stream>>>(
            j, Wk1n, out0h, wih1h, bsum1, xp1, hst, cst, hsm);
    }

    k_fc<<<dim3(64), dim3(32), 0, stream>>>(hsm, fc_w, fc_b, out);
}